// Round 4
// baseline (950.089 us; speedup 1.0000x reference)
//
#include <hip/hip_runtime.h>
#include <hip/hip_bf16.h>
#include <stdint.h>

#define DEVI __device__ __forceinline__

typedef __bf16 bf16x8 __attribute__((ext_vector_type(8)));
typedef float f32x4 __attribute__((ext_vector_type(4)));

DEVI float b2f(unsigned short u) { union { unsigned int i; float f; } v; v.i = ((unsigned int)u) << 16; return v.f; }
DEVI unsigned short f2b(float f) {
  union { unsigned int i; float f; } v; v.f = f;
  unsigned int r = (v.i + 0x7fffu + ((v.i >> 16) & 1u)) >> 16;
  return (unsigned short)r;
}

#define NEGINF (-__builtin_inff())

// async global->LDS, 16B per lane; LDS dst = uniform base + lane*16
DEVI void gl2lds16(const unsigned short* g, unsigned short* l) {
  __builtin_amdgcn_global_load_lds(
      (const __attribute__((address_space(1))) unsigned int*)g,
      (__attribute__((address_space(3))) unsigned int*)l, 16, 0, 0);
}

// ---------------------------------------------------------------------------
// Runtime dtype detection. flags[0]: f32 inputs; flags[1]: byte-packed masks.
// ---------------------------------------------------------------------------
__global__ __launch_bounds__(256) void detect_flags(
    const unsigned int* __restrict__ xw, const unsigned int* __restrict__ mw,
    int* __restrict__ flags) {
  const int t = threadIdx.x;
  int cnt = 0, big = 0;
  for (int i = t; i < 4096; i += 256) {
    unsigned int w = xw[i];
    unsigned short lo = (unsigned short)(w & 0xffffu);
    float a = fabsf(b2f(lo));
    cnt += ((lo == 0) || (a >= 1e-8f && a <= 256.f)) ? 1 : 0;
    big |= (mw[i] > 1u) ? 1 : 0;
  }
  for (int o = 32; o; o >>= 1) { cnt += __shfl_down(cnt, o); big |= __shfl_down(big, o); }
  __shared__ int sc[4], sb[4];
  if ((t & 63) == 0) { sc[t >> 6] = cnt; sb[t >> 6] = big; }
  __syncthreads();
  if (t == 0) {
    flags[0] = (sc[0] + sc[1] + sc[2] + sc[3] < 2048) ? 1 : 0;
    flags[1] = (sb[0] | sb[1] | sb[2] | sb[3]);
  }
}

__global__ __launch_bounds__(256) void cvt_bf16(
    const void* __restrict__ src, unsigned short* __restrict__ dst, int n,
    const int* __restrict__ flags) {
  const int f32mode = flags[0];
  int idx = (blockIdx.x * 256 + threadIdx.x) * 4;
  if (idx >= n) return;
  if (f32mode) {
    const float* s = (const float*)src;
    float4 v = *(const float4*)(s + idx);
    dst[idx] = f2b(v.x); dst[idx + 1] = f2b(v.y);
    dst[idx + 2] = f2b(v.z); dst[idx + 3] = f2b(v.w);
  } else {
    *(uint2*)(dst + idx) = *(const uint2*)((const unsigned short*)src + idx);
  }
}

// Batched small tensors (ng,nb,bq,bkv,bco,bada,bqkv,bo,b1,b2) -> contiguous dst
struct P10 { const void* p[10]; };
__global__ __launch_bounds__(256) void cvt_small(P10 ps, unsigned short* __restrict__ dst,
                                                 const int* __restrict__ flags) {
  const int offs[11] = {0, 1024, 2048, 3072, 5120, 6144, 12288, 15360, 16384, 20480, 21504};
  int idx = blockIdx.x * 256 + threadIdx.x;
  if (idx >= 21504) return;
  int seg = 0;
#pragma unroll
  for (int i = 1; i < 10; ++i) seg += (idx >= offs[i]) ? 1 : 0;
  int local = idx - offs[seg];
  float v = flags[0] ? ((const float*)ps.p[seg])[local]
                     : b2f(((const unsigned short*)ps.p[seg])[local]);
  dst[idx] = f2b(v);
}

// Fused convert + transpose: W (K,N) src dtype -> WT (N,K) bf16
__global__ __launch_bounds__(256) void transpose_cvt(
    const void* __restrict__ W, unsigned short* __restrict__ WT, int K, int N,
    const int* __restrict__ flags) {
  __shared__ __attribute__((aligned(16))) unsigned short tile[32][33];
  const int f32m = flags[0];
  int k0 = blockIdx.x * 32, n0 = blockIdx.y * 32;
  int tx = threadIdx.x & 31, ty = threadIdx.x >> 5;
  for (int i = ty; i < 32; i += 8) {
    size_t si = (size_t)(k0 + i) * N + n0 + tx;
    tile[i][tx] = f32m ? f2b(((const float*)W)[si]) : ((const unsigned short*)W)[si];
  }
  __syncthreads();
  for (int i = ty; i < 32; i += 8) WT[(size_t)(n0 + i) * K + k0 + tx] = tile[tx][i];
}

// Pack 3 bool masks (2048x1024 each) into bit-words (2048x16 u64 each)
struct P3 { const void* p[3]; };
__global__ __launch_bounds__(256) void pack_mask3(P3 ms, unsigned long long* __restrict__ bits,
                                                  const int* __restrict__ flags) {
  const int bytemode = flags[1];
  const void* m = ms.p[blockIdx.y];
  unsigned long long* out = bits + (size_t)blockIdx.y * 32768;
  int wv = blockIdx.x * 4 + (threadIdx.x >> 6);
  int lane = threadIdx.x & 63;
  for (int w = 0; w < 16; ++w) {
    int v;
    if (bytemode) v = ((const unsigned char*)m)[(size_t)wv * 1024 + w * 64 + lane];
    else          v = ((const int*)m)[(size_t)wv * 1024 + w * 64 + lane];
    unsigned long long b = __ballot(v != 0);
    if (lane == 0) out[(size_t)wv * 16 + w] = b;
  }
}

// V transpose to [bh][64(d)][T]: dst[(bh*64+d)*T + t] = src[(rowOff+b*T+t)*stride + colBase + h*64 + d]
__global__ __launch_bounds__(256) void vtrans(
    const unsigned short* __restrict__ src, unsigned short* __restrict__ dst,
    int T, int stride, int colBase, int rowOff) {
  __shared__ __attribute__((aligned(16))) unsigned short tile[64][65];
  const int bh = blockIdx.y, b = bh >> 4, h = bh & 15;
  const int t0 = blockIdx.x * 64;
  const int t = threadIdx.x;
#pragma unroll
  for (int it = 0; it < 2; ++it) {
    int idx = it * 256 + t; int r = idx >> 3, c8 = (idx & 7) * 8;
    uint4 d4 = *(const uint4*)(src + (size_t)(rowOff + b * T + t0 + r) * stride + colBase + h * 64 + c8);
    const unsigned short* e = (const unsigned short*)&d4;
#pragma unroll
    for (int i = 0; i < 8; ++i) tile[r][c8 + i] = e[i];
  }
  __syncthreads();
#pragma unroll
  for (int it = 0; it < 2; ++it) {
    int idx = it * 256 + t; int d = idx >> 3, c8 = (idx & 7) * 8;
    unsigned short tmp[8];
#pragma unroll
    for (int i = 0; i < 8; ++i) tmp[i] = tile[c8 + i][d];
    *(uint4*)(dst + ((size_t)(bh * 64 + d)) * T + t0 + c8) = *(const uint4*)tmp;
  }
}

// ---------------------------------------------------------------------------
// LayerNorm + ncond affine
// ---------------------------------------------------------------------------
__global__ __launch_bounds__(256) void ln_affine(
    const unsigned short* __restrict__ xs, const unsigned short* __restrict__ xh,
    const unsigned short* __restrict__ gw, const unsigned short* __restrict__ bw,
    unsigned short* __restrict__ lnx, unsigned short* __restrict__ xn) {
  const int row = blockIdx.x;
  const unsigned short* xp = (row < 2048) ? xs + (size_t)row * 1024 : xh + (size_t)(row - 2048) * 1024;
  const int t = threadIdx.x;
  float v[4]; float s = 0.f, ss = 0.f;
#pragma unroll
  for (int i = 0; i < 4; ++i) { float x = b2f(xp[i * 256 + t]); v[i] = x; s += x; ss += x * x; }
  for (int o = 32; o; o >>= 1) { s += __shfl_down(s, o); ss += __shfl_down(ss, o); }
  __shared__ float red[2][4];
  const int wv = t >> 6, lane = t & 63;
  if (lane == 0) { red[0][wv] = s; red[1][wv] = ss; }
  __syncthreads();
  s = red[0][0] + red[0][1] + red[0][2] + red[0][3];
  ss = red[1][0] + red[1][1] + red[1][2] + red[1][3];
  const float mean = s * (1.f / 1024.f);
  const float var = fmaxf(ss * (1.f / 1024.f) - mean * mean, 0.f);
  const float rstd = rsqrtf(var + 1e-6f);
  const size_t ro = (size_t)row * 1024;
#pragma unroll
  for (int i = 0; i < 4; ++i) {
    int c = i * 256 + t;
    float n = (v[i] - mean) * rstd;
    lnx[ro + c] = f2b(n);
    xn[ro + c] = f2b(n * b2f(gw[c]) + b2f(bw[c]));
  }
}

__global__ __launch_bounds__(256) void mod_ms(
    const unsigned short* __restrict__ lnx, const unsigned short* __restrict__ gada,
    unsigned short* __restrict__ ms) {
  const size_t idx = ((size_t)blockIdx.x * 256 + threadIdx.x) * 4;
  const int row = (int)(idx >> 10), c = (int)(idx & 1023);
  const size_t gb = (size_t)row * 6144;
#pragma unroll
  for (int i = 0; i < 4; ++i) {
    float sh = b2f(gada[gb + c + i]);
    float sc = b2f(gada[gb + 1024 + c + i]);
    ms[idx + i] = f2b(b2f(lnx[idx + i]) * (1.f + sc) + sh);
  }
}

__global__ __launch_bounds__(256) void ln_mod(
    const float* __restrict__ x1, const unsigned short* __restrict__ gada,
    unsigned short* __restrict__ m2) {
  const int row = blockIdx.x;
  const float* xp = x1 + (size_t)row * 1024;
  const int t = threadIdx.x;
  float v[4]; float s = 0.f, ss = 0.f;
#pragma unroll
  for (int i = 0; i < 4; ++i) { float x = xp[i * 256 + t]; v[i] = x; s += x; ss += x * x; }
  for (int o = 32; o; o >>= 1) { s += __shfl_down(s, o); ss += __shfl_down(ss, o); }
  __shared__ float red[2][4];
  const int wv = t >> 6, lane = t & 63;
  if (lane == 0) { red[0][wv] = s; red[1][wv] = ss; }
  __syncthreads();
  s = red[0][0] + red[0][1] + red[0][2] + red[0][3];
  ss = red[1][0] + red[1][1] + red[1][2] + red[1][3];
  const float mean = s * (1.f / 1024.f);
  const float var = fmaxf(ss * (1.f / 1024.f) - mean * mean, 0.f);
  const float rstd = rsqrtf(var + 1e-6f);
  const size_t gb = (size_t)row * 6144;
#pragma unroll
  for (int i = 0; i < 4; ++i) {
    int c = i * 256 + t;
    float n = (v[i] - mean) * rstd;
    float sh = b2f(gada[gb + 3072 + c]);
    float sc = b2f(gada[gb + 4096 + c]);
    m2[(size_t)row * 1024 + c] = f2b(n * (1.f + sc) + sh);
  }
}

// ---------------------------------------------------------------------------
// MFMA GEMM, m97-style global_load_lds staging (LDK=32, no pad).
// ---------------------------------------------------------------------------
enum { EPI_BF16 = 0, EPI_SILU, EPI_GELU, EPI_GATE_XRES, EPI_GATE_OUT };

template <int EPI>
__global__ __launch_bounds__(256) void gemm_bt(
    const unsigned short* __restrict__ A, const unsigned short* __restrict__ BT,
    const unsigned short* __restrict__ bias, void* __restrict__ out,
    int M, int N, int K,
    const unsigned short* __restrict__ gate,
    const void* __restrict__ res0, const void* __restrict__ res1,
    const int* __restrict__ oflags) {
  __shared__ __attribute__((aligned(16))) unsigned short As[128 * 32];
  __shared__ __attribute__((aligned(16))) unsigned short Bs[128 * 32];
  const int m0 = blockIdx.x * 128, n0 = blockIdx.y * 128;
  const int t = threadIdx.x;
  const int wave = t >> 6, lane = t & 63;
  const int wm = (wave >> 1) * 64, wn = (wave & 1) * 64;
  const int l16 = lane & 15, quad = lane >> 4;
  f32x4 acc[4][4] = {};

  const int lr = lane >> 2, lc = (lane & 3) * 8;
  const unsigned short* gA = A + (size_t)(m0 + wave * 32 + lr) * K + lc;
  const unsigned short* gB = BT + (size_t)(n0 + wave * 32 + lr) * K + lc;
  unsigned short* lA = &As[wave * 32 * 32];
  unsigned short* lB = &Bs[wave * 32 * 32];

  for (int k0 = 0; k0 < K; k0 += 32) {
    __syncthreads();
    gl2lds16(gA + k0, lA);
    gl2lds16(gA + (size_t)16 * K + k0, lA + 512);
    gl2lds16(gB + k0, lB);
    gl2lds16(gB + (size_t)16 * K + k0, lB + 512);
    __syncthreads();
    bf16x8 af[4], bf[4];
#pragma unroll
    for (int i = 0; i < 4; ++i) af[i] = *(const bf16x8*)(const void*)&As[(wm + i * 16 + l16) * 32 + quad * 8];
#pragma unroll
    for (int j = 0; j < 4; ++j) bf[j] = *(const bf16x8*)(const void*)&Bs[(wn + j * 16 + l16) * 32 + quad * 8];
#pragma unroll
    for (int i = 0; i < 4; ++i)
#pragma unroll
      for (int j = 0; j < 4; ++j)
        acc[i][j] = __builtin_amdgcn_mfma_f32_16x16x32_bf16(af[i], bf[j], acc[i][j], 0, 0, 0);
  }

#pragma unroll
  for (int i = 0; i < 4; ++i) {
    const int gm = m0 + wm + i * 16 + quad * 4;
#pragma unroll
    for (int j = 0; j < 4; ++j) {
      const int gn = n0 + wn + j * 16 + l16;
      const float bv = b2f(bias[gn]);
#pragma unroll
      for (int r = 0; r < 4; ++r) {
        const int gmr = gm + r;
        float v = acc[i][j][r] + bv;
        const size_t oi = (size_t)gmr * N + gn;
        if constexpr (EPI == EPI_BF16) {
          ((unsigned short*)out)[oi] = f2b(v);
        } else if constexpr (EPI == EPI_SILU) {
          ((unsigned short*)out)[oi] = f2b(v / (1.f + __expf(-v)));
        } else if constexpr (EPI == EPI_GELU) {
          float u = 0.7978845608028654f * (v + 0.044715f * v * v * v);
          float th = 1.f - 2.f / (__expf(2.f * u) + 1.f);
          ((unsigned short*)out)[oi] = f2b(0.5f * v * (1.f + th));
        } else if constexpr (EPI == EPI_GATE_XRES) {
          float g = b2f(gate[(size_t)gmr * 6144 + gn]);
          const unsigned short* xr = (gmr < 2048) ? (const unsigned short*)res0 : (const unsigned short*)res1;
          float x = b2f(xr[(size_t)(gmr & 2047) * 1024 + gn]);
          ((float*)out)[oi] = x + g * v;
        } else {
          float g = b2f(gate[(size_t)gmr * 6144 + gn]);
          float x = ((const float*)res0)[oi];
          float r2 = x + g * v;
          if (oflags[0]) ((float*)out)[oi] = r2;
          else ((unsigned short*)out)[oi] = f2b(r2);
        }
      }
    }
  }
}

// ---------------------------------------------------------------------------
// Barrier-free MFMA flash attention. Q/K frags + PV B-frags (from pre-
// transposed V^T [bh][d][T]) are direct global 16B loads; only per-wave
// P round-trip uses LDS.
// ---------------------------------------------------------------------------

__global__ __launch_bounds__(256) void cross_attn_mfma(
    const unsigned short* __restrict__ q, const unsigned short* __restrict__ kv,
    const unsigned short* __restrict__ vT, unsigned short* __restrict__ y) {
  constexpr int LDP = 72;
  __shared__ __attribute__((aligned(16))) unsigned short Ps[4][16 * LDP];
  const int bid = blockIdx.x;
  const int tt = bid & 15, h = (bid >> 4) & 15, b = (bid >> 8) & 1, st = bid >> 9;
  const int t = threadIdx.x, wv = t >> 6, lane = t & 63;
  const int l16 = lane & 15, quad = lane >> 4;
  const int rowbase = st * 2048 + b * 1024 + tt * 64 + wv * 16;
  const unsigned short* qp = q + (size_t)(rowbase + l16) * 1024 + h * 64 + quad * 8;
  bf16x8 aq0 = *(const bf16x8*)(qp);
  bf16x8 aq1 = *(const bf16x8*)(qp + 32);
  const unsigned short* kb = kv + (size_t)b * (256 * 2048) + h * 64;
  const unsigned short* vb = vT + (size_t)(b * 16 + h) * 64 * 256;  // [d][256]
  float m_st[4] = {NEGINF, NEGINF, NEGINF, NEGINF};
  float l_st[4] = {0.f, 0.f, 0.f, 0.f};
  f32x4 o[4] = {};
  for (int ck = 0; ck < 4; ++ck) {
    const int s0 = ck * 64;
    f32x4 s[4];
#pragma unroll
    for (int j = 0; j < 4; ++j) {
      const unsigned short* kp = kb + (size_t)(s0 + j * 16 + l16) * 2048 + quad * 8;
      bf16x8 bk0 = *(const bf16x8*)(kp);
      bf16x8 bk1 = *(const bf16x8*)(kp + 32);
      f32x4 z = {};
      z = __builtin_amdgcn_mfma_f32_16x16x32_bf16(aq0, bk0, z, 0, 0, 0);
      z = __builtin_amdgcn_mfma_f32_16x16x32_bf16(aq1, bk1, z, 0, 0, 0);
      s[j] = z;
    }
#pragma unroll
    for (int r = 0; r < 4; ++r) {
      float mx = NEGINF;
#pragma unroll
      for (int j = 0; j < 4; ++j) { float sv = s[j][r] * 0.125f; s[j][r] = sv; mx = fmaxf(mx, sv); }
#pragma unroll
      for (int o2 = 8; o2; o2 >>= 1) mx = fmaxf(mx, __shfl_xor(mx, o2));
      const float mn = fmaxf(m_st[r], mx);
      const float alpha = __expf(m_st[r] - mn);
      float rs = 0.f;
#pragma unroll
      for (int j = 0; j < 4; ++j) { float p = __expf(s[j][r] - mn); s[j][r] = p; rs += p; }
#pragma unroll
      for (int o2 = 8; o2; o2 >>= 1) rs += __shfl_xor(rs, o2);
      m_st[r] = mn;
      l_st[r] = l_st[r] * alpha + rs;
#pragma unroll
      for (int jd = 0; jd < 4; ++jd) o[jd][r] *= alpha;
#pragma unroll
      for (int j = 0; j < 4; ++j)
        Ps[wv][(quad * 4 + r) * LDP + j * 16 + l16] = f2b(s[j][r]);
    }
    bf16x8 ap0 = *(const bf16x8*)(const void*)&Ps[wv][l16 * LDP + quad * 8];
    bf16x8 ap1 = *(const bf16x8*)(const void*)&Ps[wv][l16 * LDP + 32 + quad * 8];
#pragma unroll
    for (int jd = 0; jd < 4; ++jd) {
      const unsigned short* vp = vb + (size_t)(jd * 16 + l16) * 256 + s0 + quad * 8;
      bf16x8 bv0 = *(const bf16x8*)(vp);
      bf16x8 bv1 = *(const bf16x8*)(vp + 32);
      o[jd] = __builtin_amdgcn_mfma_f32_16x16x32_bf16(ap0, bv0, o[jd], 0, 0, 0);
      o[jd] = __builtin_amdgcn_mfma_f32_16x16x32_bf16(ap1, bv1, o[jd], 0, 0, 0);
    }
  }
#pragma unroll
  for (int r = 0; r < 4; ++r) {
    const float inv = (l_st[r] > 0.f) ? 1.f / l_st[r] : 0.f;
#pragma unroll
    for (int jd = 0; jd < 4; ++jd)
      y[(size_t)(rowbase + quad * 4 + r) * 1024 + h * 64 + jd * 16 + l16] = f2b(o[jd][r] * inv);
  }
}

__global__ __launch_bounds__(256) void star_attn_mfma(
    const unsigned short* __restrict__ qkv, const unsigned short* __restrict__ vT,
    const unsigned long long* __restrict__ depb, unsigned short* __restrict__ y) {
  constexpr int LDP = 72;
  __shared__ __attribute__((aligned(16))) unsigned short Ps[4][16 * LDP];
  const int bid = blockIdx.x;
  const int tt = bid & 15, h = (bid >> 4) & 15, b = bid >> 8;
  const int t = threadIdx.x, wv = t >> 6, lane = t & 63;
  const int l16 = lane & 15, quad = lane >> 4;
  const int t0 = tt * 64;
  const int rowbase = b * 1024 + t0 + wv * 16;
  const unsigned short* qp = qkv + (size_t)(rowbase + l16) * 3072 + h * 64 + quad * 8;
  bf16x8 aq0 = *(const bf16x8*)(qp);
  bf16x8 aq1 = *(const bf16x8*)(qp + 32);
  const unsigned short* kb = qkv + (size_t)(b * 1024) * 3072 + 1024 + h * 64;
  const unsigned short* vb = vT + (size_t)(b * 16 + h) * 64 * 1024;  // [d][1024]
  float m_st[4] = {NEGINF, NEGINF, NEGINF, NEGINF};
  float l_st[4] = {0.f, 0.f, 0.f, 0.f};
  f32x4 o[4] = {};
  for (int ck = 0; ck <= tt; ++ck) {
    const int s0 = ck * 64;
    unsigned long long dwv[4];
#pragma unroll
    for (int r = 0; r < 4; ++r)
      dwv[r] = depb[(size_t)(rowbase + quad * 4 + r) * 16 + ck];
    f32x4 s[4];
#pragma unroll
    for (int j = 0; j < 4; ++j) {
      const unsigned short* kp = kb + (size_t)(s0 + j * 16 + l16) * 3072 + quad * 8;
      bf16x8 bk0 = *(const bf16x8*)(kp);
      bf16x8 bk1 = *(const bf16x8*)(kp + 32);
      f32x4 z = {};
      z = __builtin_amdgcn_mfma_f32_16x16x32_bf16(aq0, bk0, z, 0, 0, 0);
      z = __builtin_amdgcn_mfma_f32_16x16x32_bf16(aq1, bk1, z, 0, 0, 0);
      s[j] = z;
    }
#pragma unroll
    for (int r = 0; r < 4; ++r) {
      const int trow = t0 + wv * 16 + quad * 4 + r;
      float mx = NEGINF;
#pragma unroll
      for (int j = 0; j < 4; ++j) {
        const int kg = s0 + j * 16 + l16;
        bool ok = (kg <= trow) && ((dwv[r] >> (j * 16 + l16)) & 1ull);
        float sv = ok ? s[j][r] * 0.125f : NEGINF;
        s[j][r] = sv;
        mx = fmaxf(mx, sv);
      }
#pragma unroll
      for (int o2 = 8; o2; o2 >>= 1) mx = fmaxf(mx, __shfl_xor(mx, o2));
      const float mn = fmaxf(m_st[r], mx);
      const bool dead = (mn == NEGINF);
      const float alpha = dead ? 1.f : __expf(m_st[r] - mn);
      float rs = 0.f;
#pragma unroll
      for (int j = 0; j < 4; ++j) {
        float p = dead ? 0.f : __expf(s[j][r] - mn);
        s[j][r] = p;
        rs += p;
      }
#pragma unroll
      for (int o2 = 8; o2; o2 >>= 1) rs += __shfl_xor(rs, o2);
      m_st[r] = mn;
      l_st[r] = l_st[r] * alpha + rs;
#pragma unroll
      for (int jd = 0; jd < 4; ++jd) o[jd][r] *= alpha;
#pragma unroll
      for (int j = 0; j < 4; ++j)
        Ps[wv][(quad * 4 + r) * LDP + j * 16 + l16] = f2b(s[j][r]);
    }
    bf16x8 ap0 = *(const bf16x8*)(const void*)&Ps[wv][l16 * LDP + quad * 8];
    bf16x8 ap1 = *(const bf16x8*)(const void*)&Ps[wv][l16 * LDP + 32 + quad * 8];
#pragma unroll
    for (int jd = 0; jd < 4; ++jd) {
      const unsigned short* vp = vb + (size_t)(jd * 16 + l16) * 1024 + s0 + quad * 8;
      bf16x8 bv0 = *(const bf16x8*)(vp);
      bf16x8 bv1 = *(const bf16x8*)(vp + 32);
      o[jd] = __builtin_amdgcn_mfma_f32_16x16x32_bf16(ap0, bv0, o[jd], 0, 0, 0);
      o[jd] = __builtin_amdgcn_mfma_f32_16x16x32_bf16(ap1, bv1, o[jd], 0, 0, 0);
    }
  }
#pragma unroll
  for (int r = 0; r < 4; ++r) {
    const float inv = (l_st[r] > 0.f) ? 1.f / l_st[r] : 0.f;
#pragma unroll
    for (int jd = 0; jd < 4; ++jd)
      y[(size_t)(rowbase + quad * 4 + r) * 1024 + h * 64 + jd * 16 + l16] = f2b(o[jd][r] * inv);
  }
}

// Hat: key space = [star chunk | hat chunk] (128 slots); wave-uniform segment
// skip via __ballot on mask words.
__global__ __launch_bounds__(256) void hat_attn_mfma(
    const unsigned short* __restrict__ qkv,
    const unsigned short* __restrict__ vsT, const unsigned short* __restrict__ vhT,
    const unsigned long long* __restrict__ starb, const unsigned long long* __restrict__ hatb,
    const unsigned long long* __restrict__ depb, unsigned short* __restrict__ y) {
  constexpr int LDP = 136;
  __shared__ __attribute__((aligned(16))) unsigned short Ps[4][16 * LDP];
  const int bid = blockIdx.x;
  const int tt = bid & 15, h = (bid >> 4) & 15, b = bid >> 8;
  const int t = threadIdx.x, wv = t >> 6, lane = t & 63;
  const int l16 = lane & 15, quad = lane >> 4;
  const int t0 = tt * 64;
  const int rowbase = b * 1024 + t0 + wv * 16;
  const unsigned short* qp = qkv + (size_t)(2048 + rowbase + l16) * 3072 + h * 64 + quad * 8;
  bf16x8 aq0 = *(const bf16x8*)(qp);
  bf16x8 aq1 = *(const bf16x8*)(qp + 32);
  const unsigned short* ksb = qkv + (size_t)(b * 1024) * 3072 + 1024 + h * 64;
  const unsigned short* khb = qkv + (size_t)(2048 + b * 1024) * 3072 + 1024 + h * 64;
  const unsigned short* vsb = vsT + (size_t)(b * 16 + h) * 64 * 1024;
  const unsigned short* vhb = vhT + (size_t)(b * 16 + h) * 64 * 1024;
  float m_st[4] = {NEGINF, NEGINF, NEGINF, NEGINF};
  float l_st[4] = {0.f, 0.f, 0.f, 0.f};
  f32x4 o[4] = {};
  for (int ck = 0; ck < 16; ++ck) {
    const int s0 = ck * 64;
    unsigned long long swv[4], hwv[4], dwv[4];
#pragma unroll
    for (int r = 0; r < 4; ++r) {
      const size_t mrow = (size_t)(rowbase + quad * 4 + r) * 16 + ck;
      swv[r] = starb[mrow]; hwv[r] = hatb[mrow]; dwv[r] = depb[mrow];
    }
    const bool anyS = __ballot((swv[0] | swv[1] | swv[2] | swv[3]) != 0ull) != 0ull;
    const bool anyH = __ballot((hwv[0] | hwv[1] | hwv[2] | hwv[3]) != 0ull) != 0ull;
    if (!anyS && !anyH) continue;
    f32x4 s[8];
    if (anyS) {
#pragma unroll
      for (int j = 0; j < 4; ++j) {
        const unsigned short* kp = ksb + (size_t)(s0 + j * 16 + l16) * 3072 + quad * 8;
        bf16x8 bk0 = *(const bf16x8*)(kp);
        bf16x8 bk1 = *(const bf16x8*)(kp + 32);
        f32x4 z = {};
        z = __builtin_amdgcn_mfma_f32_16x16x32_bf16(aq0, bk0, z, 0, 0, 0);
        z = __builtin_amdgcn_mfma_f32_16x16x32_bf16(aq1, bk1, z, 0, 0, 0);
        s[j] = z;
      }
    }
    if (anyH) {
#pragma unroll
      for (int j = 4; j < 8; ++j) {
        const unsigned short* kp = khb + (size_t)(s0 + (j - 4) * 16 + l16) * 3072 + quad * 8;
        bf16x8 bk0 = *(const bf16x8*)(kp);
        bf16x8 bk1 = *(const bf16x8*)(kp + 32);
        f32x4 z = {};
        z = __builtin_amdgcn_mfma_f32_16x16x32_bf16(aq0, bk0, z, 0, 0, 0);
        z = __builtin_amdgcn_mfma_f32_16x16x32_bf16(aq1, bk1, z, 0, 0, 0);
        s[j] = z;
      }
    }
#pragma unroll
    for (int r = 0; r < 4; ++r) {
      float mx = NEGINF;
#pragma unroll
      for (int j = 0; j < 8; ++j) {
        const bool segOn = (j < 4) ? anyS : anyH;
        float sv = NEGINF;
        if (segOn) {
          const int kl = (j & 3) * 16 + l16;
          unsigned long long mword = (j < 4) ? swv[r] : hwv[r];
          bool ok = (((mword >> kl) & 1ull) & ((dwv[r] >> kl) & 1ull)) != 0;
          sv = ok ? s[j][r] * 0.125f : NEGINF;
        }
        s[j][r] = sv;
        mx = fmaxf(mx, sv);
      }
#pragma unroll
      for (int o2 = 8; o2; o2 >>= 1) mx = fmaxf(mx, __shfl_xor(mx, o2));
      const float mn = fmaxf(m_st[r], mx);
      const bool dead = (mn == NEGINF);
      const float alpha = dead ? 1.f : __expf(m_st[r] - mn);
      float rs = 0.f;
#pragma unroll
      for (int j = 0; j < 8; ++j) {
        const bool segOn = (j < 4) ? anyS : anyH;
        if (segOn) {
          float p = dead ? 0.f : __expf(s[j][r] - mn);
          s[j][r] = p;
          rs += p;
        }
      }
#pragma unroll
      for (int o2 = 8; o2; o2 >>= 1) rs += __shfl_xor(rs, o2);
      m_st[r] = mn;
      l_st[r] = l_st[r] * alpha + rs;
#pragma unroll
      for (int jd = 0; jd < 4; ++jd) o[jd][r] *= alpha;
#pragma unroll
      for (int j = 0; j < 8; ++j) {
        const bool segOn = (j < 4) ? anyS : anyH;
        if (segOn) Ps[wv][(quad * 4 + r) * LDP + j * 16 + l16] = f2b(s[j][r]);
      }
    }
    if (anyS) {
      bf16x8 ap0 = *(const bf16x8*)(const void*)&Ps[wv][l16 * LDP + quad * 8];
      bf16x8 ap1 = *(const bf16x8*)(const void*)&Ps[wv][l16 * LDP + 32 + quad * 8];
#pragma unroll
      for (int jd = 0; jd < 4; ++jd) {
        const unsigned short* vp = vsb + (size_t)(jd * 16 + l16) * 1024 + s0 + quad * 8;
        bf16x8 bv0 = *(const bf16x8*)(vp);
        bf16x8 bv1 = *(const bf16x8*)(vp + 32);
        o[jd] = __builtin_amdgcn_mfma_f32_16x16x32_bf16(ap0, bv0, o[jd], 0, 0, 0);
        o[jd] = __builtin_amdgcn_mfma_f32_16x16x32_bf16(ap1, bv1, o[jd], 0, 0, 0);
      }
    }
    if (anyH) {
      bf16x8 ap2 = *(const bf16x8*)(const void*)&Ps[wv][l16 * LDP + 64 + quad * 8];
      bf16x8 ap3 = *(const bf16x8*)(const void*)&Ps[wv][l16 * LDP + 96 + quad * 8];
#pragma unroll
      for (int jd = 0; jd < 4; ++jd) {
        const unsigned short* vp = vhb + (size_t)(jd * 16 + l16) * 1024 + s0 + quad * 8;
        bf16x8 bv0 = *(const bf16x8*)(vp);
        bf16x8 bv1 = *(const bf16x8*)(vp + 32);
        o[jd] = __builtin_amdgcn_mfma_f32_16x16x32_bf16(ap2, bv0, o[jd], 0, 0, 0);
        o[jd] = __builtin_amdgcn_mfma_f32_16x16x32_bf16(ap3, bv1, o[jd], 0, 0, 0);
      }
    }
  }
#pragma unroll
  for (int r = 0; r < 4; ++r) {
    const float inv = (l_st[r] > 0.f) ? 1.f / l_st[r] : 0.f;
#pragma unroll
    for (int jd = 0; jd < 4; ++jd)
      y[(size_t)(2048 + rowbase + quad * 4 + r) * 1024 + h * 64 + jd * 16 + l16] = f2b(o[jd][r] * inv);
  }
}

// ---------------------------------------------------------------------------
extern "C" void kernel_launch(void* const* d_in, const int* in_sizes, int n_in,
                              void* d_out, int out_size, void* d_ws, size_t ws_size,
                              hipStream_t stream) {
  const void* xs = d_in[0];
  const void* xh = d_in[1];
  const void* cc = d_in[2];
  const void* mstar = d_in[3];
  const void* mhat = d_in[4];
  const void* mdep = d_in[5];
  const void* ng = d_in[6];
  const void* nb = d_in[7];
  const void* Wq = d_in[8];
  const void* bq = d_in[9];
  const void* Wkv = d_in[10];
  const void* bkv = d_in[11];
  const void* Wco = d_in[12];
  const void* bco = d_in[13];
  const void* Wada = d_in[14];
  const void* bada = d_in[15];
  const void* Wqkv = d_in[16];
  const void* bqkv = d_in[17];
  const void* Wo = d_in[18];
  const void* bo = d_in[19];
  const void* W1 = d_in[20];
  const void* b1 = d_in[21];
  const void* W2 = d_in[22];
  const void* b2 = d_in[23];
  (void)in_sizes; (void)n_in; (void)out_size; (void)ws_size;

  char* ws = (char*)d_ws;
  size_t off = 0;
  auto alloc = [&](size_t bytes) -> char* {
    char* p = ws + off;
    off += (bytes + 255) & ~(size_t)255;
    return p;
  };
  int* flags = (int*)alloc(256);
  unsigned short* smallb = (unsigned short*)alloc(21504 * 2);
  unsigned short* ngb = smallb, *nbb = smallb + 1024, *bqb = smallb + 2048,
      *bkvb = smallb + 3072, *bcob = smallb + 5120, *badab = smallb + 6144,
      *bqkvb = smallb + 12288, *bob = smallb + 15360, *b1b = smallb + 16384,
      *b2b = smallb + 20480;
  unsigned short* WqT = (unsigned short*)alloc(1048576ull * 2);
  unsigned short* WkvT = (unsigned short*)alloc(2097152ull * 2);
  unsigned short* WcoT = (unsigned short*)alloc(1048576ull * 2);
  unsigned short* WadaT = (unsigned short*)alloc(6291456ull * 2);
  unsigned short* WqkvT = (unsigned short*)alloc(3145728ull * 2);
  unsigned short* WoT = (unsigned short*)alloc(1048576ull * 2);
  unsigned short* W1T = (unsigned short*)alloc(4194304ull * 2);
  unsigned short* W2T = (unsigned short*)alloc(4194304ull * 2);
  unsigned short* xsb = (unsigned short*)alloc(2097152ull * 2);
  unsigned short* xhb = (unsigned short*)alloc(2097152ull * 2);
  unsigned short* xn = (unsigned short*)alloc(4194304ull * 2);
  unsigned short* qb = (unsigned short*)alloc(4194304ull * 2);
  unsigned short* kvb = (unsigned short*)alloc(1048576ull * 2);
  unsigned short* gada = (unsigned short*)alloc(25165824ull * 2);
  unsigned short* msb = (unsigned short*)alloc(4194304ull * 2);
  unsigned short* qkvb = (unsigned short*)alloc(12582912ull * 2);
  float* x1 = (float*)alloc(4194304ull * 4);
  unsigned short* hid = (unsigned short*)alloc(16777216ull * 2);
  unsigned long long* mb = (unsigned long long*)alloc(3ull * 32768 * 8);
  unsigned short* kvT = (unsigned short*)alloc(524288ull * 2);
  unsigned short* vstT = (unsigned short*)alloc(2097152ull * 2);
  unsigned short* vhtT = (unsigned short*)alloc(2097152ull * 2);

  unsigned long long* sbits = mb;
  unsigned long long* hbits = mb + 32768;
  unsigned long long* dbits = mb + 65536;
  unsigned short* ccb = hid;              // dead before hid written
  unsigned short* lnx = hid + 1048576;    // dead before hid written
  unsigned short* yca = xn;
  unsigned short* silub = qb;
  unsigned short* yat = msb;

  dim3 blk(256);
  detect_flags<<<1, blk, 0, stream>>>((const unsigned int*)xs, (const unsigned int*)mdep, flags);

  cvt_bf16<<<2048, blk, 0, stream>>>(xs, xsb, 2097152, flags);
  cvt_bf16<<<2048, blk, 0, stream>>>(xh, xhb, 2097152, flags);
  cvt_bf16<<<512, blk, 0, stream>>>(cc, ccb, 524288, flags);
  P10 ps10; ps10.p[0] = ng; ps10.p[1] = nb; ps10.p[2] = bq; ps10.p[3] = bkv;
  ps10.p[4] = bco; ps10.p[5] = bada; ps10.p[6] = bqkv; ps10.p[7] = bo;
  ps10.p[8] = b1; ps10.p[9] = b2;
  cvt_small<<<84, blk, 0, stream>>>(ps10, smallb, flags);

  transpose_cvt<<<dim3(32, 32), blk, 0, stream>>>(Wq, WqT, 1024, 1024, flags);
  transpose_cvt<<<dim3(32, 64), blk, 0, stream>>>(Wkv, WkvT, 1024, 2048, flags);
  transpose_cvt<<<dim3(32, 32), blk, 0, stream>>>(Wco, WcoT, 1024, 1024, flags);
  transpose_cvt<<<dim3(32, 192), blk, 0, stream>>>(Wada, WadaT, 1024, 6144, flags);
  transpose_cvt<<<dim3(32, 96), blk, 0, stream>>>(Wqkv, WqkvT, 1024, 3072, flags);
  transpose_cvt<<<dim3(32, 32), blk, 0, stream>>>(Wo, WoT, 1024, 1024, flags);
  transpose_cvt<<<dim3(32, 128), blk, 0, stream>>>(W1, W1T, 1024, 4096, flags);
  transpose_cvt<<<dim3(128, 32), blk, 0, stream>>>(W2, W2T, 4096, 1024, flags);

  P3 ps3; ps3.p[0] = mstar; ps3.p[1] = mhat; ps3.p[2] = mdep;
  pack_mask3<<<dim3(512, 3), blk, 0, stream>>>(ps3, mb, flags);

  ln_affine<<<4096, blk, 0, stream>>>(xsb, xhb, ngb, nbb, lnx, xn);
  gemm_bt<EPI_BF16><<<dim3(32, 8), blk, 0, stream>>>(xn, WqT, bqb, qb, 4096, 1024, 1024, nullptr, nullptr, nullptr, nullptr);
  gemm_bt<EPI_BF16><<<dim3(4, 16), blk, 0, stream>>>(ccb, WkvT, bkvb, kvb, 512, 2048, 1024, nullptr, nullptr, nullptr, nullptr);
  vtrans<<<dim3(4, 32), blk, 0, stream>>>(kvb, kvT, 256, 2048, 1024, 0);
  cross_attn_mfma<<<1024, blk, 0, stream>>>(qb, kvb, kvT, yca);
  gemm_bt<EPI_SILU><<<dim3(32, 8), blk, 0, stream>>>(yca, WcoT, bcob, silub, 4096, 1024, 1024, nullptr, nullptr, nullptr, nullptr);
  gemm_bt<EPI_BF16><<<dim3(32, 48), blk, 0, stream>>>(silub, WadaT, badab, gada, 4096, 6144, 1024, nullptr, nullptr, nullptr, nullptr);
  mod_ms<<<4096, blk, 0, stream>>>(lnx, gada, msb);
  gemm_bt<EPI_BF16><<<dim3(32, 24), blk, 0, stream>>>(msb, WqkvT, bqkvb, qkvb, 4096, 3072, 1024, nullptr, nullptr, nullptr, nullptr);
  vtrans<<<dim3(16, 32), blk, 0, stream>>>(qkvb, vstT, 1024, 3072, 2048, 0);
  vtrans<<<dim3(16, 32), blk, 0, stream>>>(qkvb, vhtT, 1024, 3072, 2048, 2048);
  star_attn_mfma<<<512, blk, 0, stream>>>(qkvb, vstT, dbits, yat);
  hat_attn_mfma<<<512, blk, 0, stream>>>(qkvb, vstT, vhtT, sbits, hbits, dbits, yat);
  gemm_bt<EPI_GATE_XRES><<<dim3(32, 8), blk, 0, stream>>>(yat, WoT, bob, x1, 4096, 1024, 1024, gada + 2048, xsb, xhb, nullptr);
  ln_mod<<<4096, blk, 0, stream>>>(x1, gada, msb);
  gemm_bt<EPI_GELU><<<dim3(32, 32), blk, 0, stream>>>(msb, W1T, b1b, hid, 4096, 4096, 1024, nullptr, nullptr, nullptr, nullptr);
  gemm_bt<EPI_GATE_OUT><<<dim3(32, 8), blk, 0, stream>>>(hid, W2T, b2b, d_out, 4096, 1024, 4096, gada + 5120, x1, nullptr, flags);
}

// Round 5
// 901.817 us; speedup vs baseline: 1.0535x; 1.0535x over previous
//
#include <hip/hip_runtime.h>
#include <hip/hip_bf16.h>
#include <stdint.h>

#define DEVI __device__ __forceinline__

typedef __bf16 bf16x8 __attribute__((ext_vector_type(8)));
typedef float f32x4 __attribute__((ext_vector_type(4)));

DEVI float b2f(unsigned short u) { union { unsigned int i; float f; } v; v.i = ((unsigned int)u) << 16; return v.f; }
DEVI unsigned short f2b(float f) {
  union { unsigned int i; float f; } v; v.f = f;
  unsigned int r = (v.i + 0x7fffu + ((v.i >> 16) & 1u)) >> 16;
  return (unsigned short)r;
}

#define NEGINF (-__builtin_inff())

// async global->LDS, 16B per lane; LDS dst = wave-uniform base + lane*16
DEVI void gl2lds16(const unsigned short* g, unsigned short* l) {
  __builtin_amdgcn_global_load_lds(
      (const __attribute__((address_space(1))) unsigned int*)g,
      (__attribute__((address_space(3))) unsigned int*)l, 16, 0, 0);
}

// ---------------------------------------------------------------------------
// Runtime dtype detection. flags[0]: f32 inputs; flags[1]: byte-packed masks.
// ---------------------------------------------------------------------------
__global__ __launch_bounds__(256) void detect_flags(
    const unsigned int* __restrict__ xw, const unsigned int* __restrict__ mw,
    int* __restrict__ flags) {
  const int t = threadIdx.x;
  int cnt = 0, big = 0;
  for (int i = t; i < 4096; i += 256) {
    unsigned int w = xw[i];
    unsigned short lo = (unsigned short)(w & 0xffffu);
    float a = fabsf(b2f(lo));
    cnt += ((lo == 0) || (a >= 1e-8f && a <= 256.f)) ? 1 : 0;
    big |= (mw[i] > 1u) ? 1 : 0;
  }
  for (int o = 32; o; o >>= 1) { cnt += __shfl_down(cnt, o); big |= __shfl_down(big, o); }
  __shared__ int sc[4], sb[4];
  if ((t & 63) == 0) { sc[t >> 6] = cnt; sb[t >> 6] = big; }
  __syncthreads();
  if (t == 0) {
    flags[0] = (sc[0] + sc[1] + sc[2] + sc[3] < 2048) ? 1 : 0;
    flags[1] = (sb[0] | sb[1] | sb[2] | sb[3]);
  }
}

__global__ __launch_bounds__(256) void cvt_bf16(
    const void* __restrict__ src, unsigned short* __restrict__ dst, int n,
    const int* __restrict__ flags) {
  const int f32mode = flags[0];
  int idx = (blockIdx.x * 256 + threadIdx.x) * 4;
  if (idx >= n) return;
  if (f32mode) {
    const float* s = (const float*)src;
    float4 v = *(const float4*)(s + idx);
    dst[idx] = f2b(v.x); dst[idx + 1] = f2b(v.y);
    dst[idx + 2] = f2b(v.z); dst[idx + 3] = f2b(v.w);
  } else {
    *(uint2*)(dst + idx) = *(const uint2*)((const unsigned short*)src + idx);
  }
}

struct P10 { const void* p[10]; };
__global__ __launch_bounds__(256) void cvt_small(P10 ps, unsigned short* __restrict__ dst,
                                                 const int* __restrict__ flags) {
  const int offs[11] = {0, 1024, 2048, 3072, 5120, 6144, 12288, 15360, 16384, 20480, 21504};
  int idx = blockIdx.x * 256 + threadIdx.x;
  if (idx >= 21504) return;
  int seg = 0;
#pragma unroll
  for (int i = 1; i < 10; ++i) seg += (idx >= offs[i]) ? 1 : 0;
  int local = idx - offs[seg];
  float v = flags[0] ? ((const float*)ps.p[seg])[local]
                     : b2f(((const unsigned short*)ps.p[seg])[local]);
  dst[idx] = f2b(v);
}

__global__ __launch_bounds__(256) void transpose_cvt(
    const void* __restrict__ W, unsigned short* __restrict__ WT, int K, int N,
    const int* __restrict__ flags) {
  __shared__ __attribute__((aligned(16))) unsigned short tile[32][33];
  const int f32m = flags[0];
  int k0 = blockIdx.x * 32, n0 = blockIdx.y * 32;
  int tx = threadIdx.x & 31, ty = threadIdx.x >> 5;
  for (int i = ty; i < 32; i += 8) {
    size_t si = (size_t)(k0 + i) * N + n0 + tx;
    tile[i][tx] = f32m ? f2b(((const float*)W)[si]) : ((const unsigned short*)W)[si];
  }
  __syncthreads();
  for (int i = ty; i < 32; i += 8) WT[(size_t)(n0 + i) * K + k0 + tx] = tile[tx][i];
}

struct P3 { const void* p[3]; };
__global__ __launch_bounds__(256) void pack_mask3(P3 ms, unsigned long long* __restrict__ bits,
                                                  const int* __restrict__ flags) {
  const int bytemode = flags[1];
  const void* m = ms.p[blockIdx.y];
  unsigned long long* out = bits + (size_t)blockIdx.y * 32768;
  int wv = blockIdx.x * 4 + (threadIdx.x >> 6);
  int lane = threadIdx.x & 63;
  for (int w = 0; w < 16; ++w) {
    int v;
    if (bytemode) v = ((const unsigned char*)m)[(size_t)wv * 1024 + w * 64 + lane];
    else          v = ((const int*)m)[(size_t)wv * 1024 + w * 64 + lane];
    unsigned long long b = __ballot(v != 0);
    if (lane == 0) out[(size_t)wv * 16 + w] = b;
  }
}

// Per-(b,tt) per-chunk segment-activity flags for hat: bit0=star, bit1=hat.
__global__ __launch_bounds__(256) void hat_blockflags(
    const unsigned long long* __restrict__ starb, const unsigned long long* __restrict__ hatb,
    int* __restrict__ bf) {
  const int bt = blockIdx.x;  // b*16+tt, 32 blocks
  const int b = bt >> 4, tt = bt & 15;
  const int t = threadIdx.x, wv = t >> 6, lane = t & 63;
  const int t0 = tt * 64;
  for (int k = 0; k < 4; ++k) {
    int ck = wv * 4 + k;
    unsigned long long sw = starb[(size_t)(b * 1024 + t0 + lane) * 16 + ck];
    unsigned long long hw = hatb[(size_t)(b * 1024 + t0 + lane) * 16 + ck];
    int f = (__ballot(sw != 0ull) ? 1 : 0) | (__ballot(hw != 0ull) ? 2 : 0);
    if (lane == 0) bf[bt * 16 + ck] = f;
  }
}

// V transpose to [bh][64(d)][T]
__global__ __launch_bounds__(256) void vtrans(
    const unsigned short* __restrict__ src, unsigned short* __restrict__ dst,
    int T, int stride, int colBase, int rowOff) {
  __shared__ __attribute__((aligned(16))) unsigned short tile[64][65];
  const int bh = blockIdx.y, b = bh >> 4, h = bh & 15;
  const int t0 = blockIdx.x * 64;
  const int t = threadIdx.x;
#pragma unroll
  for (int it = 0; it < 2; ++it) {
    int idx = it * 256 + t; int r = idx >> 3, c8 = (idx & 7) * 8;
    uint4 d4 = *(const uint4*)(src + (size_t)(rowOff + b * T + t0 + r) * stride + colBase + h * 64 + c8);
    const unsigned short* e = (const unsigned short*)&d4;
#pragma unroll
    for (int i = 0; i < 8; ++i) tile[r][c8 + i] = e[i];
  }
  __syncthreads();
#pragma unroll
  for (int it = 0; it < 2; ++it) {
    int idx = it * 256 + t; int d = idx >> 3, c8 = (idx & 7) * 8;
    unsigned short tmp[8];
#pragma unroll
    for (int i = 0; i < 8; ++i) tmp[i] = tile[c8 + i][d];
    *(uint4*)(dst + ((size_t)(bh * 64 + d)) * T + t0 + c8) = *(const uint4*)tmp;
  }
}

// ---------------------------------------------------------------------------
// LayerNorm + modulation kernels
// ---------------------------------------------------------------------------
__global__ __launch_bounds__(256) void ln_affine(
    const unsigned short* __restrict__ xs, const unsigned short* __restrict__ xh,
    const unsigned short* __restrict__ gw, const unsigned short* __restrict__ bw,
    unsigned short* __restrict__ lnx, unsigned short* __restrict__ xn) {
  const int row = blockIdx.x;
  const unsigned short* xp = (row < 2048) ? xs + (size_t)row * 1024 : xh + (size_t)(row - 2048) * 1024;
  const int t = threadIdx.x;
  float v[4]; float s = 0.f, ss = 0.f;
#pragma unroll
  for (int i = 0; i < 4; ++i) { float x = b2f(xp[i * 256 + t]); v[i] = x; s += x; ss += x * x; }
  for (int o = 32; o; o >>= 1) { s += __shfl_down(s, o); ss += __shfl_down(ss, o); }
  __shared__ float red[2][4];
  const int wv = t >> 6, lane = t & 63;
  if (lane == 0) { red[0][wv] = s; red[1][wv] = ss; }
  __syncthreads();
  s = red[0][0] + red[0][1] + red[0][2] + red[0][3];
  ss = red[1][0] + red[1][1] + red[1][2] + red[1][3];
  const float mean = s * (1.f / 1024.f);
  const float var = fmaxf(ss * (1.f / 1024.f) - mean * mean, 0.f);
  const float rstd = rsqrtf(var + 1e-6f);
  const size_t ro = (size_t)row * 1024;
#pragma unroll
  for (int i = 0; i < 4; ++i) {
    int c = i * 256 + t;
    float n = (v[i] - mean) * rstd;
    lnx[ro + c] = f2b(n);
    xn[ro + c] = f2b(n * b2f(gw[c]) + b2f(bw[c]));
  }
}

__global__ __launch_bounds__(256) void mod_ms(
    const unsigned short* __restrict__ lnx, const unsigned short* __restrict__ gada,
    unsigned short* __restrict__ ms) {
  const size_t idx = ((size_t)blockIdx.x * 256 + threadIdx.x) * 4;
  const int row = (int)(idx >> 10), c = (int)(idx & 1023);
  const size_t gb = (size_t)row * 6144;
#pragma unroll
  for (int i = 0; i < 4; ++i) {
    float sh = b2f(gada[gb + c + i]);
    float sc = b2f(gada[gb + 1024 + c + i]);
    ms[idx + i] = f2b(b2f(lnx[idx + i]) * (1.f + sc) + sh);
  }
}

__global__ __launch_bounds__(256) void ln_mod(
    const float* __restrict__ x1, const unsigned short* __restrict__ gada,
    unsigned short* __restrict__ m2) {
  const int row = blockIdx.x;
  const float* xp = x1 + (size_t)row * 1024;
  const int t = threadIdx.x;
  float v[4]; float s = 0.f, ss = 0.f;
#pragma unroll
  for (int i = 0; i < 4; ++i) { float x = xp[i * 256 + t]; v[i] = x; s += x; ss += x * x; }
  for (int o = 32; o; o >>= 1) { s += __shfl_down(s, o); ss += __shfl_down(ss, o); }
  __shared__ float red[2][4];
  const int wv = t >> 6, lane = t & 63;
  if (lane == 0) { red[0][wv] = s; red[1][wv] = ss; }
  __syncthreads();
  s = red[0][0] + red[0][1] + red[0][2] + red[0][3];
  ss = red[1][0] + red[1][1] + red[1][2] + red[1][3];
  const float mean = s * (1.f / 1024.f);
  const float var = fmaxf(ss * (1.f / 1024.f) - mean * mean, 0.f);
  const float rstd = rsqrtf(var + 1e-6f);
  const size_t gb = (size_t)row * 6144;
#pragma unroll
  for (int i = 0; i < 4; ++i) {
    int c = i * 256 + t;
    float n = (v[i] - mean) * rstd;
    float sh = b2f(gada[gb + 3072 + c]);
    float sc = b2f(gada[gb + 4096 + c]);
    m2[(size_t)row * 1024 + c] = f2b(n * (1.f + sc) + sh);
  }
}

// ---------------------------------------------------------------------------
// MFMA GEMM, m97-style global_load_lds staging (unchanged from R4).
// ---------------------------------------------------------------------------
enum { EPI_BF16 = 0, EPI_SILU, EPI_GELU, EPI_GATE_XRES, EPI_GATE_OUT };

template <int EPI>
__global__ __launch_bounds__(256) void gemm_bt(
    const unsigned short* __restrict__ A, const unsigned short* __restrict__ BT,
    const unsigned short* __restrict__ bias, void* __restrict__ out,
    int M, int N, int K,
    const unsigned short* __restrict__ gate,
    const void* __restrict__ res0, const void* __restrict__ res1,
    const int* __restrict__ oflags) {
  __shared__ __attribute__((aligned(16))) unsigned short As[128 * 32];
  __shared__ __attribute__((aligned(16))) unsigned short Bs[128 * 32];
  const int m0 = blockIdx.x * 128, n0 = blockIdx.y * 128;
  const int t = threadIdx.x;
  const int wave = t >> 6, lane = t & 63;
  const int wm = (wave >> 1) * 64, wn = (wave & 1) * 64;
  const int l16 = lane & 15, quad = lane >> 4;
  f32x4 acc[4][4] = {};

  const int lr = lane >> 2, lc = (lane & 3) * 8;
  const unsigned short* gA = A + (size_t)(m0 + wave * 32 + lr) * K + lc;
  const unsigned short* gB = BT + (size_t)(n0 + wave * 32 + lr) * K + lc;
  unsigned short* lA = &As[wave * 32 * 32];
  unsigned short* lB = &Bs[wave * 32 * 32];

  for (int k0 = 0; k0 < K; k0 += 32) {
    __syncthreads();
    gl2lds16(gA + k0, lA);
    gl2lds16(gA + (size_t)16 * K + k0, lA + 512);
    gl2lds16(gB + k0, lB);
    gl2lds16(gB + (size_t)16 * K + k0, lB + 512);
    __syncthreads();
    bf16x8 af[4], bf[4];
#pragma unroll
    for (int i = 0; i < 4; ++i) af[i] = *(const bf16x8*)(const void*)&As[(wm + i * 16 + l16) * 32 + quad * 8];
#pragma unroll
    for (int j = 0; j < 4; ++j) bf[j] = *(const bf16x8*)(const void*)&Bs[(wn + j * 16 + l16) * 32 + quad * 8];
#pragma unroll
    for (int i = 0; i < 4; ++i)
#pragma unroll
      for (int j = 0; j < 4; ++j)
        acc[i][j] = __builtin_amdgcn_mfma_f32_16x16x32_bf16(af[i], bf[j], acc[i][j], 0, 0, 0);
  }

#pragma unroll
  for (int i = 0; i < 4; ++i) {
    const int gm = m0 + wm + i * 16 + quad * 4;
#pragma unroll
    for (int j = 0; j < 4; ++j) {
      const int gn = n0 + wn + j * 16 + l16;
      const float bv = b2f(bias[gn]);
#pragma unroll
      for (int r = 0; r < 4; ++r) {
        const int gmr = gm + r;
        float v = acc[i][j][r] + bv;
        const size_t oi = (size_t)gmr * N + gn;
        if constexpr (EPI == EPI_BF16) {
          ((unsigned short*)out)[oi] = f2b(v);
        } else if constexpr (EPI == EPI_SILU) {
          ((unsigned short*)out)[oi] = f2b(v / (1.f + __expf(-v)));
        } else if constexpr (EPI == EPI_GELU) {
          float u = 0.7978845608028654f * (v + 0.044715f * v * v * v);
          float th = 1.f - 2.f / (__expf(2.f * u) + 1.f);
          ((unsigned short*)out)[oi] = f2b(0.5f * v * (1.f + th));
        } else if constexpr (EPI == EPI_GATE_XRES) {
          float g = b2f(gate[(size_t)gmr * 6144 + gn]);
          const unsigned short* xr = (gmr < 2048) ? (const unsigned short*)res0 : (const unsigned short*)res1;
          float x = b2f(xr[(size_t)(gmr & 2047) * 1024 + gn]);
          ((float*)out)[oi] = x + g * v;
        } else {
          float g = b2f(gate[(size_t)gmr * 6144 + gn]);
          float x = ((const float*)res0)[oi];
          float r2 = x + g * v;
          if (oflags[0]) ((float*)out)[oi] = r2;
          else ((unsigned short*)out)[oi] = f2b(r2);
        }
      }
    }
  }
}

// ---------------------------------------------------------------------------
// MFMA flash attention, block-cooperative LDS staging of K and V^T tiles.
// LDS row stride 72 elems (144 B, 16B-aligned). P aliases the K buffer
// (K dead after QK; P wave-private -> 3 barriers per chunk).
// ---------------------------------------------------------------------------

__global__ __launch_bounds__(256) void cross_attn_mfma(
    const unsigned short* __restrict__ q, const unsigned short* __restrict__ kv,
    const unsigned short* __restrict__ vT, unsigned short* __restrict__ y) {
  __shared__ __attribute__((aligned(16))) unsigned short Ks[64 * 72];  // alias: P
  __shared__ __attribute__((aligned(16))) unsigned short Vt[64 * 72];
  const int bid = blockIdx.x;
  const int tt = bid & 15, h = (bid >> 4) & 15, b = (bid >> 8) & 1, st = bid >> 9;
  const int t = threadIdx.x, wv = t >> 6, lane = t & 63;
  const int l16 = lane & 15, quad = lane >> 4;
  const int rowbase = st * 2048 + b * 1024 + tt * 64 + wv * 16;
  const unsigned short* qp = q + (size_t)(rowbase + l16) * 1024 + h * 64 + quad * 8;
  bf16x8 aq0 = *(const bf16x8*)(qp);
  bf16x8 aq1 = *(const bf16x8*)(qp + 32);
  const unsigned short* kb = kv + (size_t)b * (256 * 2048) + h * 64;
  const unsigned short* vb = vT + (size_t)(b * 16 + h) * 64 * 256;  // [d][256]
  float m_st[4] = {NEGINF, NEGINF, NEGINF, NEGINF};
  float l_st[4] = {0.f, 0.f, 0.f, 0.f};
  f32x4 o[4] = {};
  for (int ck = 0; ck < 4; ++ck) {
    const int s0 = ck * 64;
    __syncthreads();
#pragma unroll
    for (int it = 0; it < 2; ++it) {
      int id = it * 256 + t; int row = id >> 3, g8 = (id & 7) * 8;
      *(uint4*)&Ks[row * 72 + g8] = *(const uint4*)(kb + (size_t)(s0 + row) * 2048 + g8);
      *(uint4*)&Vt[row * 72 + g8] = *(const uint4*)(vb + (size_t)row * 256 + s0 + g8);
    }
    __syncthreads();
    f32x4 s[4];
#pragma unroll
    for (int j = 0; j < 4; ++j) {
      bf16x8 bk0 = *(const bf16x8*)(const void*)&Ks[(j * 16 + l16) * 72 + quad * 8];
      bf16x8 bk1 = *(const bf16x8*)(const void*)&Ks[(j * 16 + l16) * 72 + 32 + quad * 8];
      f32x4 z = {};
      z = __builtin_amdgcn_mfma_f32_16x16x32_bf16(aq0, bk0, z, 0, 0, 0);
      z = __builtin_amdgcn_mfma_f32_16x16x32_bf16(aq1, bk1, z, 0, 0, 0);
      s[j] = z;
    }
    __syncthreads();  // all waves done reading K before P overlays it
    float pv[4][4];
#pragma unroll
    for (int r = 0; r < 4; ++r) {
      float mx = NEGINF;
#pragma unroll
      for (int j = 0; j < 4; ++j) { float sv = s[j][r] * 0.125f; s[j][r] = sv; mx = fmaxf(mx, sv); }
#pragma unroll
      for (int o2 = 8; o2; o2 >>= 1) mx = fmaxf(mx, __shfl_xor(mx, o2));
      const float mn = fmaxf(m_st[r], mx);
      const float alpha = __expf(m_st[r] - mn);
      float rs = 0.f;
#pragma unroll
      for (int j = 0; j < 4; ++j) { float p = __expf(s[j][r] - mn); pv[j][r] = p; rs += p; }
#pragma unroll
      for (int o2 = 8; o2; o2 >>= 1) rs += __shfl_xor(rs, o2);
      m_st[r] = mn;
      l_st[r] = l_st[r] * alpha + rs;
#pragma unroll
      for (int jd = 0; jd < 4; ++jd) o[jd][r] *= alpha;
#pragma unroll
      for (int j = 0; j < 4; ++j)
        Ks[(wv * 16 + quad * 4 + r) * 72 + j * 16 + l16] = f2b(pv[j][r]);
    }
    // P is wave-private: no barrier needed before reading it back
    bf16x8 ap0 = *(const bf16x8*)(const void*)&Ks[(wv * 16 + l16) * 72 + quad * 8];
    bf16x8 ap1 = *(const bf16x8*)(const void*)&Ks[(wv * 16 + l16) * 72 + 32 + quad * 8];
#pragma unroll
    for (int jd = 0; jd < 4; ++jd) {
      bf16x8 bv0 = *(const bf16x8*)(const void*)&Vt[(jd * 16 + l16) * 72 + quad * 8];
      bf16x8 bv1 = *(const bf16x8*)(const void*)&Vt[(jd * 16 + l16) * 72 + 32 + quad * 8];
      o[jd] = __builtin_amdgcn_mfma_f32_16x16x32_bf16(ap0, bv0, o[jd], 0, 0, 0);
      o[jd] = __builtin_amdgcn_mfma_f32_16x16x32_bf16(ap1, bv1, o[jd], 0, 0, 0);
    }
  }
#pragma unroll
  for (int r = 0; r < 4; ++r) {
    const float inv = (l_st[r] > 0.f) ? 1.f / l_st[r] : 0.f;
#pragma unroll
    for (int jd = 0; jd < 4; ++jd)
      y[(size_t)(rowbase + quad * 4 + r) * 1024 + h * 64 + jd * 16 + l16] = f2b(o[jd][r] * inv);
  }
}

__global__ __launch_bounds__(256) void star_attn_mfma(
    const unsigned short* __restrict__ qkv, const unsigned short* __restrict__ vT,
    const unsigned long long* __restrict__ depb, unsigned short* __restrict__ y) {
  __shared__ __attribute__((aligned(16))) unsigned short Ks[64 * 72];  // alias: P
  __shared__ __attribute__((aligned(16))) unsigned short Vt[64 * 72];
  const int bid = blockIdx.x;
  const int tt = bid & 15, h = (bid >> 4) & 15, b = bid >> 8;
  const int t = threadIdx.x, wv = t >> 6, lane = t & 63;
  const int l16 = lane & 15, quad = lane >> 4;
  const int t0 = tt * 64;
  const int rowbase = b * 1024 + t0 + wv * 16;
  const unsigned short* qp = qkv + (size_t)(rowbase + l16) * 3072 + h * 64 + quad * 8;
  bf16x8 aq0 = *(const bf16x8*)(qp);
  bf16x8 aq1 = *(const bf16x8*)(qp + 32);
  const unsigned short* kb = qkv + (size_t)(b * 1024) * 3072 + 1024 + h * 64;
  const unsigned short* vb = vT + (size_t)(b * 16 + h) * 64 * 1024;  // [d][1024]
  float m_st[4] = {NEGINF, NEGINF, NEGINF, NEGINF};
  float l_st[4] = {0.f, 0.f, 0.f, 0.f};
  f32x4 o[4] = {};
  for (int ck = 0; ck <= tt; ++ck) {
    const int s0 = ck * 64;
    __syncthreads();
#pragma unroll
    for (int it = 0; it < 2; ++it) {
      int id = it * 256 + t; int row = id >> 3, g8 = (id & 7) * 8;
      *(uint4*)&Ks[row * 72 + g8] = *(const uint4*)(kb + (size_t)(s0 + row) * 3072 + g8);
      *(uint4*)&Vt[row * 72 + g8] = *(const uint4*)(vb + (size_t)row * 1024 + s0 + g8);
    }
    __syncthreads();
    unsigned long long dwv[4];
#pragma unroll
    for (int r = 0; r < 4; ++r)
      dwv[r] = depb[(size_t)(rowbase + quad * 4 + r) * 16 + ck];
    f32x4 s[4];
#pragma unroll
    for (int j = 0; j < 4; ++j) {
      bf16x8 bk0 = *(const bf16x8*)(const void*)&Ks[(j * 16 + l16) * 72 + quad * 8];
      bf16x8 bk1 = *(const bf16x8*)(const void*)&Ks[(j * 16 + l16) * 72 + 32 + quad * 8];
      f32x4 z = {};
      z = __builtin_amdgcn_mfma_f32_16x16x32_bf16(aq0, bk0, z, 0, 0, 0);
      z = __builtin_amdgcn_mfma_f32_16x16x32_bf16(aq1, bk1, z, 0, 0, 0);
      s[j] = z;
    }
    __syncthreads();
#pragma unroll
    for (int r = 0; r < 4; ++r) {
      const int trow = t0 + wv * 16 + quad * 4 + r;
      float mx = NEGINF;
#pragma unroll
      for (int j = 0; j < 4; ++j) {
        const int kg = s0 + j * 16 + l16;
        bool ok = (kg <= trow) && ((dwv[r] >> (j * 16 + l16)) & 1ull);
        float sv = ok ? s[j][r] * 0.125f : NEGINF;
        s[j][r] = sv;
        mx = fmaxf(mx, sv);
      }
#pragma unroll
      for (int o2 = 8; o2; o2 >>= 1) mx = fmaxf(mx, __shfl_xor(mx, o2));
      const float mn = fmaxf(m_st[r], mx);
      const bool dead = (mn == NEGINF);
      const float alpha = dead ? 1.f : __expf(m_st[r] - mn);
      float rs = 0.f;
#pragma unroll
      for (int j = 0; j < 4; ++j) {
        float p = dead ? 0.f : __expf(s[j][r] - mn);
        s[j][r] = p;
        rs += p;
      }
#pragma unroll
      for (int o2 = 8; o2; o2 >>= 1) rs += __shfl_xor(rs, o2);
      m_st[r] = mn;
      l_st[r] = l_st[r] * alpha + rs;
#pragma unroll
      for (int jd = 0; jd < 4; ++jd) o[jd][r] *= alpha;
#pragma unroll
      for (int j = 0; j < 4; ++j)
        Ks[(wv * 16 + quad * 4 + r) * 72 + j * 16 + l16] = f2b(s[j][r]);
    }
    bf16x8 ap0 = *(const bf16x8*)(const void*)&Ks[(wv * 16 + l16) * 72 + quad * 8];
    bf16x8 ap1 = *(const bf16x8*)(const void*)&Ks[(wv * 16 + l16) * 72 + 32 + quad * 8];
#pragma unroll
    for (int jd = 0; jd < 4; ++jd) {
      bf16x8 bv0 = *(const bf16x8*)(const void*)&Vt[(jd * 16 + l16) * 72 + quad * 8];
      bf16x8 bv1 = *(const bf16x8*)(const void*)&Vt[(jd * 16 + l16) * 72 + 32 + quad * 8];
      o[jd] = __builtin_amdgcn_mfma_f32_16x16x32_bf16(ap0, bv0, o[jd], 0, 0, 0);
      o[jd] = __builtin_amdgcn_mfma_f32_16x16x32_bf16(ap1, bv1, o[jd], 0, 0, 0);
    }
  }
#pragma unroll
  for (int r = 0; r < 4; ++r) {
    const float inv = (l_st[r] > 0.f) ? 1.f / l_st[r] : 0.f;
#pragma unroll
    for (int jd = 0; jd < 4; ++jd)
      y[(size_t)(rowbase + quad * 4 + r) * 1024 + h * 64 + jd * 16 + l16] = f2b(o[jd][r] * inv);
  }
}

// Hat: key space [star chunk | hat chunk]; block-uniform chunk/segment skip
// via precomputed blockflags; per-wave fine skip; P aliases Kst (18432 B).
__global__ __launch_bounds__(256) void hat_attn_mfma(
    const unsigned short* __restrict__ qkv,
    const unsigned short* __restrict__ vsT, const unsigned short* __restrict__ vhT,
    const unsigned long long* __restrict__ starb, const unsigned long long* __restrict__ hatb,
    const unsigned long long* __restrict__ depb, const int* __restrict__ bflags,
    unsigned short* __restrict__ y) {
  __shared__ __attribute__((aligned(16))) unsigned short Kst[2][64 * 72];  // alias: P (LDP=136)
  __shared__ __attribute__((aligned(16))) unsigned short Vtt[2][64 * 72];
  unsigned short* Ps = &Kst[0][0];
  const int bid = blockIdx.x;
  const int tt = bid & 15, h = (bid >> 4) & 15, b = bid >> 8;
  const int t = threadIdx.x, wv = t >> 6, lane = t & 63;
  const int l16 = lane & 15, quad = lane >> 4;
  const int t0 = tt * 64;
  const int rowbase = b * 1024 + t0 + wv * 16;
  const unsigned short* qp = qkv + (size_t)(2048 + rowbase + l16) * 3072 + h * 64 + quad * 8;
  bf16x8 aq0 = *(const bf16x8*)(qp);
  bf16x8 aq1 = *(const bf16x8*)(qp + 32);
  const unsigned short* ksb = qkv + (size_t)(b * 1024) * 3072 + 1024 + h * 64;
  const unsigned short* khb = qkv + (size_t)(2048 + b * 1024) * 3072 + 1024 + h * 64;
  const unsigned short* vsb = vsT + (size_t)(b * 16 + h) * 64 * 1024;
  const unsigned short* vhb = vhT + (size_t)(b * 16 + h) * 64 * 1024;
  float m_st[4] = {NEGINF, NEGINF, NEGINF, NEGINF};
  float l_st[4] = {0.f, 0.f, 0.f, 0.f};
  f32x4 o[4] = {};
  for (int ck = 0; ck < 16; ++ck) {
    const int bf = bflags[(b * 16 + tt) * 16 + ck];
    if (bf == 0) continue;  // block-uniform
    const int s0 = ck * 64;
    __syncthreads();  // previous chunk's P reads done before restaging
#pragma unroll
    for (int it = 0; it < 2; ++it) {
      int id = it * 256 + t; int row = id >> 3, g8 = (id & 7) * 8;
      if (bf & 1) {
        *(uint4*)&Kst[0][row * 72 + g8] = *(const uint4*)(ksb + (size_t)(s0 + row) * 3072 + g8);
        *(uint4*)&Vtt[0][row * 72 + g8] = *(const uint4*)(vsb + (size_t)row * 1024 + s0 + g8);
      }
      if (bf & 2) {
        *(uint4*)&Kst[1][row * 72 + g8] = *(const uint4*)(khb + (size_t)(s0 + row) * 3072 + g8);
        *(uint4*)&Vtt[1][row * 72 + g8] = *(const uint4*)(vhb + (size_t)row * 1024 + s0 + g8);
      }
    }
    __syncthreads();
    unsigned long long swv[4], hwv[4], dwv[4];
#pragma unroll
    for (int r = 0; r < 4; ++r) {
      const size_t mrow = (size_t)(rowbase + quad * 4 + r) * 16 + ck;
      swv[r] = starb[mrow]; hwv[r] = hatb[mrow]; dwv[r] = depb[mrow];
    }
    const bool anyS = __ballot((swv[0] | swv[1] | swv[2] | swv[3]) != 0ull) != 0ull;
    const bool anyH = __ballot((hwv[0] | hwv[1] | hwv[2] | hwv[3]) != 0ull) != 0ull;
    f32x4 s[8];
    if (anyS) {
#pragma unroll
      for (int j = 0; j < 4; ++j) {
        bf16x8 bk0 = *(const bf16x8*)(const void*)&Kst[0][(j * 16 + l16) * 72 + quad * 8];
        bf16x8 bk1 = *(const bf16x8*)(const void*)&Kst[0][(j * 16 + l16) * 72 + 32 + quad * 8];
        f32x4 z = {};
        z = __builtin_amdgcn_mfma_f32_16x16x32_bf16(aq0, bk0, z, 0, 0, 0);
        z = __builtin_amdgcn_mfma_f32_16x16x32_bf16(aq1, bk1, z, 0, 0, 0);
        s[j] = z;
      }
    }
    if (anyH) {
#pragma unroll
      for (int j = 4; j < 8; ++j) {
        bf16x8 bk0 = *(const bf16x8*)(const void*)&Kst[1][((j - 4) * 16 + l16) * 72 + quad * 8];
        bf16x8 bk1 = *(const bf16x8*)(const void*)&Kst[1][((j - 4) * 16 + l16) * 72 + 32 + quad * 8];
        f32x4 z = {};
        z = __builtin_amdgcn_mfma_f32_16x16x32_bf16(aq0, bk0, z, 0, 0, 0);
        z = __builtin_amdgcn_mfma_f32_16x16x32_bf16(aq1, bk1, z, 0, 0, 0);
        s[j] = z;
      }
    }
    __syncthreads();  // all waves done reading K before P overlays it
    if (anyS | anyH) {
#pragma unroll
      for (int r = 0; r < 4; ++r) {
        float mx = NEGINF;
#pragma unroll
        for (int j = 0; j < 8; ++j) {
          const bool segOn = (j < 4) ? anyS : anyH;
          float sv = NEGINF;
          if (segOn) {
            const int kl = (j & 3) * 16 + l16;
            unsigned long long mword = (j < 4) ? swv[r] : hwv[r];
            bool ok = (((mword >> kl) & 1ull) & ((dwv[r] >> kl) & 1ull)) != 0;
            sv = ok ? s[j][r] * 0.125f : NEGINF;
          }
          s[j][r] = sv;
          mx = fmaxf(mx, sv);
        }
#pragma unroll
        for (int o2 = 8; o2; o2 >>= 1) mx = fmaxf(mx, __shfl_xor(mx, o2));
        const float mn = fmaxf(m_st[r], mx);
        const bool dead = (mn == NEGINF);
        const float alpha = dead ? 1.f : __expf(m_st[r] - mn);
        float rs = 0.f;
#pragma unroll
        for (int j = 0; j < 8; ++j) {
          const bool segOn = (j < 4) ? anyS : anyH;
          if (segOn) { float p = dead ? 0.f : __expf(s[j][r] - mn); s[j][r] = p; rs += p; }
        }
#pragma unroll
        for (int o2 = 8; o2; o2 >>= 1) rs += __shfl_xor(rs, o2);
        m_st[r] = mn;
        l_st[r] = l_st[r] * alpha + rs;
#pragma unroll
        for (int jd = 0; jd < 4; ++jd) o[jd][r] *= alpha;
#pragma unroll
        for (int j = 0; j < 8; ++j) {
          const bool segOn = (j < 4) ? anyS : anyH;
          if (segOn) Ps[(wv * 16 + quad * 4 + r) * 136 + j * 16 + l16] = f2b(s[j][r]);
        }
      }
      // P wave-private: no barrier
      if (anyS) {
        bf16x8 ap0 = *(const bf16x8*)(const void*)&Ps[(wv * 16 + l16) * 136 + quad * 8];
        bf16x8 ap1 = *(const bf16x8*)(const void*)&Ps[(wv * 16 + l16) * 136 + 32 + quad * 8];
#pragma unroll
        for (int jd = 0; jd < 4; ++jd) {
          bf16x8 bv0 = *(const bf16x8*)(const void*)&Vtt[0][(jd * 16 + l16) * 72 + quad * 8];
          bf16x8 bv1 = *(const bf16x8*)(const void*)&Vtt[0][(jd * 16 + l16) * 72 + 32 + quad * 8];
          o[jd] = __builtin_amdgcn_mfma_f32_16x16x32_bf16(ap0, bv0, o[jd], 0, 0, 0);
          o[jd] = __builtin_amdgcn_mfma_f32_16x16x32_bf16(ap1, bv1, o[jd], 0, 0, 0);
        }
      }
      if (anyH) {
        bf16x8 ap2 = *(const bf16x8*)(const void*)&Ps[(wv * 16 + l16) * 136 + 64 + quad * 8];
        bf16x8 ap3 = *(const bf16x8*)(const void*)&Ps[(wv * 16 + l16) * 136 + 96 + quad * 8];
#pragma unroll
        for (int jd = 0; jd < 4; ++jd) {
          bf16x8 bv0 = *(const bf16x8*)(const void*)&Vtt[1][(jd * 16 + l16) * 72 + quad * 8];
          bf16x8 bv1 = *(const bf16x8*)(const void*)&Vtt[1][(jd * 16 + l16) * 72 + 32 + quad * 8];
          o[jd] = __builtin_amdgcn_mfma_f32_16x16x32_bf16(ap2, bv0, o[jd], 0, 0, 0);
          o[jd] = __builtin_amdgcn_mfma_f32_16x16x32_bf16(ap3, bv1, o[jd], 0, 0, 0);
        }
      }
    }
  }
#pragma unroll
  for (int r = 0; r < 4; ++r) {
    const float inv = (l_st[r] > 0.f) ? 1.f / l_st[r] : 0.f;
#pragma unroll
    for (int jd = 0; jd < 4; ++jd)
      y[(size_t)(2048 + rowbase + quad * 4 + r) * 1024 + h * 64 + jd * 16 + l16] = f2b(o[jd][r] * inv);
  }
}

// ---------------------------------------------------------------------------
extern "C" void kernel_launch(void* const* d_in, const int* in_sizes, int n_in,
                              void* d_out, int out_size, void* d_ws, size_t ws_size,
                              hipStream_t stream) {
  const void* xs = d_in[0];
  const void* xh = d_in[1];
  const void* cc = d_in[2];
  const void* mstar = d_in[3];
  const void* mhat = d_in[4];
  const void* mdep = d_in[5];
  const void* ng = d_in[6];
  const void* nb = d_in[7];
  const void* Wq = d_in[8];
  const void* bq = d_in[9];
  const void* Wkv = d_in[10];
  const void* bkv = d_in[11];
  const void* Wco = d_in[12];
  const void* bco = d_in[13];
  const void* Wada = d_in[14];
  const void* bada = d_in[15];
  const void* Wqkv = d_in[16];
  const void* bqkv = d_in[17];
  const void* Wo = d_in[18];
  const void* bo = d_in[19];
  const void* W1 = d_in[20];
  const void* b1 = d_in[21];
  const void* W2 = d_in[22];
  const void* b2 = d_in[23];
  (void)in_sizes; (void)n_in; (void)out_size; (void)ws_size;

  char* ws = (char*)d_ws;
  size_t off = 0;
  auto alloc = [&](size_t bytes) -> char* {
    char* p = ws + off;
    off += (bytes + 255) & ~(size_t)255;
    return p;
  };
  int* flags = (int*)alloc(256);
  int* bflags = (int*)alloc(512 * 4);
  unsigned short* smallb = (unsigned short*)alloc(21504 * 2);
  unsigned short* ngb = smallb, *nbb = smallb + 1024, *bqb = smallb + 2048,
      *bkvb = smallb + 3072, *bcob = smallb + 5120, *badab = smallb + 6144,
      *bqkvb = smallb + 12288, *bob = smallb + 15360, *b1b = smallb + 16384,
      *b2b = smallb + 20480;
  unsigned short* WqT = (unsigned short*)alloc(1048576ull * 2);
  unsigned short* WkvT = (unsigned short*)alloc(2097152ull * 2);
  unsigned short* WcoT = (unsigned short*)alloc(1048576ull * 2);
  unsigned short* WadaT = (unsigned short*)alloc(6291456ull * 2);
  unsigned short* WqkvT = (unsigned short*)alloc(3145728ull * 2);
  unsigned short* WoT = (unsigned short*)alloc(1048576ull * 2);
  unsigned short* W1T = (unsigned short*)alloc(4194304ull * 2);
  unsigned short* W2T = (unsigned short*)alloc(4194304ull * 2);
  unsigned short* xsb = (unsigned short*)alloc(2097152ull * 2);
  unsigned short* xhb = (unsigned short*)alloc(2097152ull * 2);
  unsigned short* xn = (unsigned short*)alloc(4194304ull * 2);
  unsigned short* qb = (unsigned short*)alloc(4194304ull * 2);
  unsigned short* kvb = (unsigned short*)alloc(1048576ull * 2);
  unsigned short* gada = (unsigned short*)alloc(25165824ull * 2);
  unsigned short* msb = (unsigned short*)alloc(4194304ull * 2);
  unsigned short* qkvb = (unsigned short*)alloc(12582912ull * 2);
  float* x1 = (float*)alloc(4194304ull * 4);
  unsigned short* hid = (unsigned short*)alloc(16777216ull * 2);
  unsigned long long* mb = (unsigned long long*)alloc(3ull * 32768 * 8);
  unsigned short* kvT = (unsigned short*)alloc(524288ull * 2);
  unsigned short* vstT = (unsigned short*)alloc(2097152ull * 2);
  unsigned short* vhtT = (unsigned short*)alloc(2097152ull * 2);

  unsigned long long* sbits = mb;
  unsigned long long* hbits = mb + 32768;
  unsigned long long* dbits = mb + 65536;
  unsigned short* ccb = hid;              // dead before hid written
  unsigned short* lnx = hid + 1048576;    // dead before hid written
  unsigned short* yca = xn;
  unsigned short* silub = qb;
  unsigned short* yat = msb;

  dim3 blk(256);
  detect_flags<<<1, blk, 0, stream>>>((const unsigned int*)xs, (const unsigned int*)mdep, flags);

  cvt_bf16<<<2048, blk, 0, stream>>>(xs, xsb, 2097152, flags);
  cvt_bf16<<<2048, blk, 0, stream>>>(xh, xhb, 2097152, flags);
  cvt_bf16<<<512, blk, 0, stream>>>(cc, ccb, 524288, flags);
  P10 ps10; ps10.p[0] = ng; ps10.p[1] = nb; ps10.p[2] = bq; ps10.p[3] = bkv;
  ps10.p[4] = bco; ps10.p[5] = bada; ps10.p[6] = bqkv; ps10.p[7] = bo;
  ps10.p[8] = b1; ps10.p[9] = b2;
  cvt_small<<<84, blk, 0, stream>>>(ps10, smallb, flags);

  transpose_cvt<<<dim3(32, 32), blk, 0, stream>>>(Wq, WqT, 1024, 1024, flags);
  transpose_cvt<<<dim3(32, 64), blk, 0, stream>>>(Wkv, WkvT, 1024, 2048, flags);
  transpose_cvt<<<dim3(32, 32), blk, 0, stream>>>(Wco, WcoT, 1024, 1024, flags);
  transpose_cvt<<<dim3(32, 192), blk, 0, stream>>>(Wada, WadaT, 1024, 6144, flags);
  transpose_cvt<<<dim3(32, 96), blk, 0, stream>>>(Wqkv, WqkvT, 1024, 3072, flags);
  transpose_cvt<<<dim3(32, 32), blk, 0, stream>>>(Wo, WoT, 1024, 1024, flags);
  transpose_cvt<<<dim3(32, 128), blk, 0, stream>>>(W1, W1T, 1024, 4096, flags);
  transpose_cvt<<<dim3(128, 32), blk, 0, stream>>>(W2, W2T, 4096, 1024, flags);

  P3 ps3; ps3.p[0] = mstar; ps3.p[1] = mhat; ps3.p[2] = mdep;
  pack_mask3<<<dim3(512, 3), blk, 0, stream>>>(ps3, mb, flags);
  hat_blockflags<<<32, blk, 0, stream>>>(sbits, hbits, bflags);

  ln_affine<<<4096, blk, 0, stream>>>(xsb, xhb, ngb, nbb, lnx, xn);
  gemm_bt<EPI_BF16><<<dim3(32, 8), blk, 0, stream>>>(xn, WqT, bqb, qb, 4096, 1024, 1024, nullptr, nullptr, nullptr, nullptr);
  gemm_bt<EPI_BF16><<<dim3(4, 16), blk, 0, stream>>>(ccb, WkvT, bkvb, kvb, 512, 2048, 1024, nullptr, nullptr, nullptr, nullptr);
  vtrans<<<dim3(4, 32), blk, 0, stream>>>(kvb, kvT, 256, 2048, 1024, 0);
  cross_attn_mfma<<<1024, blk, 0, stream>>>(qb, kvb, kvT, yca);
  gemm_bt<EPI_SILU><<<dim3(32, 8), blk, 0, stream>>>(yca, WcoT, bcob, silub, 4096, 1024, 1024, nullptr, nullptr, nullptr, nullptr);
  gemm_bt<EPI_BF16><<<dim3(32, 48), blk, 0, stream>>>(silub, WadaT, badab, gada, 4096, 6144, 1024, nullptr, nullptr, nullptr, nullptr);
  mod_ms<<<4096, blk, 0, stream>>>(lnx, gada, msb);
  gemm_bt<EPI_BF16><<<dim3(32, 24), blk, 0, stream>>>(msb, WqkvT, bqkvb, qkvb, 4096, 3072, 1024, nullptr, nullptr, nullptr, nullptr);
  vtrans<<<dim3(16, 32), blk, 0, stream>>>(qkvb, vstT, 1024, 3072, 2048, 0);
  vtrans<<<dim3(16, 32), blk, 0, stream>>>(qkvb, vhtT, 1024, 3072, 2048, 2048);
  star_attn_mfma<<<512, blk, 0, stream>>>(qkvb, vstT, dbits, yat);
  hat_attn_mfma<<<512, blk, 0, stream>>>(qkvb, vstT, vhtT, sbits, hbits, dbits, bflags, yat);
  gemm_bt<EPI_GATE_XRES><<<dim3(32, 8), blk, 0, stream>>>(yat, WoT, bob, x1, 4096, 1024, 1024, gada + 2048, xsb, xhb, nullptr);
  ln_mod<<<4096, blk, 0, stream>>>(x1, gada, msb);
  gemm_bt<EPI_GELU><<<dim3(32, 32), blk, 0, stream>>>(msb, W1T, b1b, hid, 4096, 4096, 1024, nullptr, nullptr, nullptr, nullptr);
  gemm_bt<EPI_GATE_OUT><<<dim3(32, 8), blk, 0, stream>>>(hid, W2T, b2b, d_out, 4096, 1024, 4096, gada + 5120, x1, nullptr, flags);
}

// Round 6
// 806.311 us; speedup vs baseline: 1.1783x; 1.1184x over previous
//
#include <hip/hip_runtime.h>
#include <hip/hip_bf16.h>
#include <stdint.h>

#define DEVI __device__ __forceinline__

typedef __bf16 bf16x8 __attribute__((ext_vector_type(8)));
typedef float f32x4 __attribute__((ext_vector_type(4)));

DEVI float b2f(unsigned short u) { union { unsigned int i; float f; } v; v.i = ((unsigned int)u) << 16; return v.f; }
DEVI unsigned short f2b(float f) {
  union { unsigned int i; float f; } v; v.f = f;
  unsigned int r = (v.i + 0x7fffu + ((v.i >> 16) & 1u)) >> 16;
  return (unsigned short)r;
}

#define NEGINF (-__builtin_inff())

// async global->LDS, 16B per lane; LDS dst = wave-uniform base + lane*16
DEVI void gl2lds16(const unsigned short* g, unsigned short* l) {
  __builtin_amdgcn_global_load_lds(
      (const __attribute__((address_space(1))) unsigned int*)g,
      (__attribute__((address_space(3))) unsigned int*)l, 16, 0, 0);
}

// ---------------------------------------------------------------------------
// Runtime dtype detection. flags[0]: f32 inputs; flags[1]: byte-packed masks.
// ---------------------------------------------------------------------------
__global__ __launch_bounds__(256) void detect_flags(
    const unsigned int* __restrict__ xw, const unsigned int* __restrict__ mw,
    int* __restrict__ flags) {
  const int t = threadIdx.x;
  int cnt = 0, big = 0;
  for (int i = t; i < 4096; i += 256) {
    unsigned int w = xw[i];
    unsigned short lo = (unsigned short)(w & 0xffffu);
    float a = fabsf(b2f(lo));
    cnt += ((lo == 0) || (a >= 1e-8f && a <= 256.f)) ? 1 : 0;
    big |= (mw[i] > 1u) ? 1 : 0;
  }
  for (int o = 32; o; o >>= 1) { cnt += __shfl_down(cnt, o); big |= __shfl_down(big, o); }
  __shared__ int sc[4], sb[4];
  if ((t & 63) == 0) { sc[t >> 6] = cnt; sb[t >> 6] = big; }
  __syncthreads();
  if (t == 0) {
    flags[0] = (sc[0] + sc[1] + sc[2] + sc[3] < 2048) ? 1 : 0;
    flags[1] = (sb[0] | sb[1] | sb[2] | sb[3]);
  }
}

__global__ __launch_bounds__(256) void cvt_bf16(
    const void* __restrict__ src, unsigned short* __restrict__ dst, int n,
    const int* __restrict__ flags) {
  const int f32mode = flags[0];
  int idx = (blockIdx.x * 256 + threadIdx.x) * 4;
  if (idx >= n) return;
  if (f32mode) {
    const float* s = (const float*)src;
    float4 v = *(const float4*)(s + idx);
    dst[idx] = f2b(v.x); dst[idx + 1] = f2b(v.y);
    dst[idx + 2] = f2b(v.z); dst[idx + 3] = f2b(v.w);
  } else {
    *(uint2*)(dst + idx) = *(const uint2*)((const unsigned short*)src + idx);
  }
}

struct P10 { const void* p[10]; };
__global__ __launch_bounds__(256) void cvt_small(P10 ps, unsigned short* __restrict__ dst,
                                                 const int* __restrict__ flags) {
  const int offs[11] = {0, 1024, 2048, 3072, 5120, 6144, 12288, 15360, 16384, 20480, 21504};
  int idx = blockIdx.x * 256 + threadIdx.x;
  if (idx >= 21504) return;
  int seg = 0;
#pragma unroll
  for (int i = 1; i < 10; ++i) seg += (idx >= offs[i]) ? 1 : 0;
  int local = idx - offs[seg];
  float v = flags[0] ? ((const float*)ps.p[seg])[local]
                     : b2f(((const unsigned short*)ps.p[seg])[local]);
  dst[idx] = f2b(v);
}

__global__ __launch_bounds__(256) void transpose_cvt(
    const void* __restrict__ W, unsigned short* __restrict__ WT, int K, int N,
    const int* __restrict__ flags) {
  __shared__ __attribute__((aligned(16))) unsigned short tile[32][33];
  const int f32m = flags[0];
  int k0 = blockIdx.x * 32, n0 = blockIdx.y * 32;
  int tx = threadIdx.x & 31, ty = threadIdx.x >> 5;
  for (int i = ty; i < 32; i += 8) {
    size_t si = (size_t)(k0 + i) * N + n0 + tx;
    tile[i][tx] = f32m ? f2b(((const float*)W)[si]) : ((const unsigned short*)W)[si];
  }
  __syncthreads();
  for (int i = ty; i < 32; i += 8) WT[(size_t)(n0 + i) * K + k0 + tx] = tile[tx][i];
}

struct P3 { const void* p[3]; };
__global__ __launch_bounds__(256) void pack_mask3(P3 ms, unsigned long long* __restrict__ bits,
                                                  const int* __restrict__ flags) {
  const int bytemode = flags[1];
  const void* m = ms.p[blockIdx.y];
  unsigned long long* out = bits + (size_t)blockIdx.y * 32768;
  int wv = blockIdx.x * 4 + (threadIdx.x >> 6);
  int lane = threadIdx.x & 63;
  for (int w = 0; w < 16; ++w) {
    int v;
    if (bytemode) v = ((const unsigned char*)m)[(size_t)wv * 1024 + w * 64 + lane];
    else          v = ((const int*)m)[(size_t)wv * 1024 + w * 64 + lane];
    unsigned long long b = __ballot(v != 0);
    if (lane == 0) out[(size_t)wv * 16 + w] = b;
  }
}

// Per-(b,tt) per-chunk segment-activity flags for hat: bit0=star, bit1=hat.
__global__ __launch_bounds__(256) void hat_blockflags(
    const unsigned long long* __restrict__ starb, const unsigned long long* __restrict__ hatb,
    int* __restrict__ bf) {
  const int bt = blockIdx.x;  // b*16+tt, 32 blocks
  const int b = bt >> 4, tt = bt & 15;
  const int t = threadIdx.x, wv = t >> 6, lane = t & 63;
  const int t0 = tt * 64;
  for (int k = 0; k < 4; ++k) {
    int ck = wv * 4 + k;
    unsigned long long sw = starb[(size_t)(b * 1024 + t0 + lane) * 16 + ck];
    unsigned long long hw = hatb[(size_t)(b * 1024 + t0 + lane) * 16 + ck];
    int f = (__ballot(sw != 0ull) ? 1 : 0) | (__ballot(hw != 0ull) ? 2 : 0);
    if (lane == 0) bf[bt * 16 + ck] = f;
  }
}

// V transpose to [bh][64(d)][T]
__global__ __launch_bounds__(256) void vtrans(
    const unsigned short* __restrict__ src, unsigned short* __restrict__ dst,
    int T, int stride, int colBase, int rowOff) {
  __shared__ __attribute__((aligned(16))) unsigned short tile[64][65];
  const int bh = blockIdx.y, b = bh >> 4, h = bh & 15;
  const int t0 = blockIdx.x * 64;
  const int t = threadIdx.x;
#pragma unroll
  for (int it = 0; it < 2; ++it) {
    int idx = it * 256 + t; int r = idx >> 3, c8 = (idx & 7) * 8;
    uint4 d4 = *(const uint4*)(src + (size_t)(rowOff + b * T + t0 + r) * stride + colBase + h * 64 + c8);
    const unsigned short* e = (const unsigned short*)&d4;
#pragma unroll
    for (int i = 0; i < 8; ++i) tile[r][c8 + i] = e[i];
  }
  __syncthreads();
#pragma unroll
  for (int it = 0; it < 2; ++it) {
    int idx = it * 256 + t; int d = idx >> 3, c8 = (idx & 7) * 8;
    unsigned short tmp[8];
#pragma unroll
    for (int i = 0; i < 8; ++i) tmp[i] = tile[c8 + i][d];
    *(uint4*)(dst + ((size_t)(bh * 64 + d)) * T + t0 + c8) = *(const uint4*)tmp;
  }
}

// ---------------------------------------------------------------------------
// LayerNorm + modulation kernels
// ---------------------------------------------------------------------------
__global__ __launch_bounds__(256) void ln_affine(
    const unsigned short* __restrict__ xs, const unsigned short* __restrict__ xh,
    const unsigned short* __restrict__ gw, const unsigned short* __restrict__ bw,
    unsigned short* __restrict__ lnx, unsigned short* __restrict__ xn) {
  const int row = blockIdx.x;
  const unsigned short* xp = (row < 2048) ? xs + (size_t)row * 1024 : xh + (size_t)(row - 2048) * 1024;
  const int t = threadIdx.x;
  float v[4]; float s = 0.f, ss = 0.f;
#pragma unroll
  for (int i = 0; i < 4; ++i) { float x = b2f(xp[i * 256 + t]); v[i] = x; s += x; ss += x * x; }
  for (int o = 32; o; o >>= 1) { s += __shfl_down(s, o); ss += __shfl_down(ss, o); }
  __shared__ float red[2][4];
  const int wv = t >> 6, lane = t & 63;
  if (lane == 0) { red[0][wv] = s; red[1][wv] = ss; }
  __syncthreads();
  s = red[0][0] + red[0][1] + red[0][2] + red[0][3];
  ss = red[1][0] + red[1][1] + red[1][2] + red[1][3];
  const float mean = s * (1.f / 1024.f);
  const float var = fmaxf(ss * (1.f / 1024.f) - mean * mean, 0.f);
  const float rstd = rsqrtf(var + 1e-6f);
  const size_t ro = (size_t)row * 1024;
#pragma unroll
  for (int i = 0; i < 4; ++i) {
    int c = i * 256 + t;
    float n = (v[i] - mean) * rstd;
    lnx[ro + c] = f2b(n);
    xn[ro + c] = f2b(n * b2f(gw[c]) + b2f(bw[c]));
  }
}

__global__ __launch_bounds__(256) void mod_ms(
    const unsigned short* __restrict__ lnx, const unsigned short* __restrict__ gada,
    unsigned short* __restrict__ ms) {
  const size_t idx = ((size_t)blockIdx.x * 256 + threadIdx.x) * 4;
  const int row = (int)(idx >> 10), c = (int)(idx & 1023);
  const size_t gb = (size_t)row * 6144;
#pragma unroll
  for (int i = 0; i < 4; ++i) {
    float sh = b2f(gada[gb + c + i]);
    float sc = b2f(gada[gb + 1024 + c + i]);
    ms[idx + i] = f2b(b2f(lnx[idx + i]) * (1.f + sc) + sh);
  }
}

__global__ __launch_bounds__(256) void ln_mod(
    const float* __restrict__ x1, const unsigned short* __restrict__ gada,
    unsigned short* __restrict__ m2) {
  const int row = blockIdx.x;
  const float* xp = x1 + (size_t)row * 1024;
  const int t = threadIdx.x;
  float v[4]; float s = 0.f, ss = 0.f;
#pragma unroll
  for (int i = 0; i < 4; ++i) { float x = xp[i * 256 + t]; v[i] = x; s += x; ss += x * x; }
  for (int o = 32; o; o >>= 1) { s += __shfl_down(s, o); ss += __shfl_down(ss, o); }
  __shared__ float red[2][4];
  const int wv = t >> 6, lane = t & 63;
  if (lane == 0) { red[0][wv] = s; red[1][wv] = ss; }
  __syncthreads();
  s = red[0][0] + red[0][1] + red[0][2] + red[0][3];
  ss = red[1][0] + red[1][1] + red[1][2] + red[1][3];
  const float mean = s * (1.f / 1024.f);
  const float var = fmaxf(ss * (1.f / 1024.f) - mean * mean, 0.f);
  const float rstd = rsqrtf(var + 1e-6f);
  const size_t gb = (size_t)row * 6144;
#pragma unroll
  for (int i = 0; i < 4; ++i) {
    int c = i * 256 + t;
    float n = (v[i] - mean) * rstd;
    float sh = b2f(gada[gb + 3072 + c]);
    float sc = b2f(gada[gb + 4096 + c]);
    m2[(size_t)row * 1024 + c] = f2b(n * (1.f + sc) + sh);
  }
}

// ---------------------------------------------------------------------------
// MFMA GEMM, m97-style global_load_lds staging (unchanged).
// ---------------------------------------------------------------------------
enum { EPI_BF16 = 0, EPI_SILU, EPI_GELU, EPI_GATE_XRES, EPI_GATE_OUT };

template <int EPI>
__global__ __launch_bounds__(256) void gemm_bt(
    const unsigned short* __restrict__ A, const unsigned short* __restrict__ BT,
    const unsigned short* __restrict__ bias, void* __restrict__ out,
    int M, int N, int K,
    const unsigned short* __restrict__ gate,
    const void* __restrict__ res0, const void* __restrict__ res1,
    const int* __restrict__ oflags) {
  __shared__ __attribute__((aligned(16))) unsigned short As[128 * 32];
  __shared__ __attribute__((aligned(16))) unsigned short Bs[128 * 32];
  const int m0 = blockIdx.x * 128, n0 = blockIdx.y * 128;
  const int t = threadIdx.x;
  const int wave = t >> 6, lane = t & 63;
  const int wm = (wave >> 1) * 64, wn = (wave & 1) * 64;
  const int l16 = lane & 15, quad = lane >> 4;
  f32x4 acc[4][4] = {};

  const int lr = lane >> 2, lc = (lane & 3) * 8;
  const unsigned short* gA = A + (size_t)(m0 + wave * 32 + lr) * K + lc;
  const unsigned short* gB = BT + (size_t)(n0 + wave * 32 + lr) * K + lc;
  unsigned short* lA = &As[wave * 32 * 32];
  unsigned short* lB = &Bs[wave * 32 * 32];

  for (int k0 = 0; k0 < K; k0 += 32) {
    __syncthreads();
    gl2lds16(gA + k0, lA);
    gl2lds16(gA + (size_t)16 * K + k0, lA + 512);
    gl2lds16(gB + k0, lB);
    gl2lds16(gB + (size_t)16 * K + k0, lB + 512);
    __syncthreads();
    bf16x8 af[4], bf[4];
#pragma unroll
    for (int i = 0; i < 4; ++i) af[i] = *(const bf16x8*)(const void*)&As[(wm + i * 16 + l16) * 32 + quad * 8];
#pragma unroll
    for (int j = 0; j < 4; ++j) bf[j] = *(const bf16x8*)(const void*)&Bs[(wn + j * 16 + l16) * 32 + quad * 8];
#pragma unroll
    for (int i = 0; i < 4; ++i)
#pragma unroll
      for (int j = 0; j < 4; ++j)
        acc[i][j] = __builtin_amdgcn_mfma_f32_16x16x32_bf16(af[i], bf[j], acc[i][j], 0, 0, 0);
  }

#pragma unroll
  for (int i = 0; i < 4; ++i) {
    const int gm = m0 + wm + i * 16 + quad * 4;
#pragma unroll
    for (int j = 0; j < 4; ++j) {
      const int gn = n0 + wn + j * 16 + l16;
      const float bv = b2f(bias[gn]);
#pragma unroll
      for (int r = 0; r < 4; ++r) {
        const int gmr = gm + r;
        float v = acc[i][j][r] + bv;
        const size_t oi = (size_t)gmr * N + gn;
        if constexpr (EPI == EPI_BF16) {
          ((unsigned short*)out)[oi] = f2b(v);
        } else if constexpr (EPI == EPI_SILU) {
          ((unsigned short*)out)[oi] = f2b(v / (1.f + __expf(-v)));
        } else if constexpr (EPI == EPI_GELU) {
          float u = 0.7978845608028654f * (v + 0.044715f * v * v * v);
          float th = 1.f - 2.f / (__expf(2.f * u) + 1.f);
          ((unsigned short*)out)[oi] = f2b(0.5f * v * (1.f + th));
        } else if constexpr (EPI == EPI_GATE_XRES) {
          float g = b2f(gate[(size_t)gmr * 6144 + gn]);
          const unsigned short* xr = (gmr < 2048) ? (const unsigned short*)res0 : (const unsigned short*)res1;
          float x = b2f(xr[(size_t)(gmr & 2047) * 1024 + gn]);
          ((float*)out)[oi] = x + g * v;
        } else {
          float g = b2f(gate[(size_t)gmr * 6144 + gn]);
          float x = ((const float*)res0)[oi];
          float r2 = x + g * v;
          if (oflags[0]) ((float*)out)[oi] = r2;
          else ((unsigned short*)out)[oi] = f2b(r2);
        }
      }
    }
  }
}

// ---------------------------------------------------------------------------
// Cross attention (unchanged from R5).
// ---------------------------------------------------------------------------
__global__ __launch_bounds__(256) void cross_attn_mfma(
    const unsigned short* __restrict__ q, const unsigned short* __restrict__ kv,
    const unsigned short* __restrict__ vT, unsigned short* __restrict__ y) {
  __shared__ __attribute__((aligned(16))) unsigned short Ks[64 * 72];  // alias: P
  __shared__ __attribute__((aligned(16))) unsigned short Vt[64 * 72];
  const int bid = blockIdx.x;
  const int tt = bid & 15, h = (bid >> 4) & 15, b = (bid >> 8) & 1, st = bid >> 9;
  const int t = threadIdx.x, wv = t >> 6, lane = t & 63;
  const int l16 = lane & 15, quad = lane >> 4;
  const int rowbase = st * 2048 + b * 1024 + tt * 64 + wv * 16;
  const unsigned short* qp = q + (size_t)(rowbase + l16) * 1024 + h * 64 + quad * 8;
  bf16x8 aq0 = *(const bf16x8*)(qp);
  bf16x8 aq1 = *(const bf16x8*)(qp + 32);
  const unsigned short* kb = kv + (size_t)b * (256 * 2048) + h * 64;
  const unsigned short* vb = vT + (size_t)(b * 16 + h) * 64 * 256;
  float m_st[4] = {NEGINF, NEGINF, NEGINF, NEGINF};
  float l_st[4] = {0.f, 0.f, 0.f, 0.f};
  f32x4 o[4] = {};
  for (int ck = 0; ck < 4; ++ck) {
    const int s0 = ck * 64;
    __syncthreads();
#pragma unroll
    for (int it = 0; it < 2; ++it) {
      int id = it * 256 + t; int row = id >> 3, g8 = (id & 7) * 8;
      *(uint4*)&Ks[row * 72 + g8] = *(const uint4*)(kb + (size_t)(s0 + row) * 2048 + g8);
      *(uint4*)&Vt[row * 72 + g8] = *(const uint4*)(vb + (size_t)row * 256 + s0 + g8);
    }
    __syncthreads();
    f32x4 s[4];
#pragma unroll
    for (int j = 0; j < 4; ++j) {
      bf16x8 bk0 = *(const bf16x8*)(const void*)&Ks[(j * 16 + l16) * 72 + quad * 8];
      bf16x8 bk1 = *(const bf16x8*)(const void*)&Ks[(j * 16 + l16) * 72 + 32 + quad * 8];
      f32x4 z = {};
      z = __builtin_amdgcn_mfma_f32_16x16x32_bf16(aq0, bk0, z, 0, 0, 0);
      z = __builtin_amdgcn_mfma_f32_16x16x32_bf16(aq1, bk1, z, 0, 0, 0);
      s[j] = z;
    }
    __syncthreads();
    float pv[4][4];
#pragma unroll
    for (int r = 0; r < 4; ++r) {
      float mx = NEGINF;
#pragma unroll
      for (int j = 0; j < 4; ++j) { float sv = s[j][r] * 0.125f; s[j][r] = sv; mx = fmaxf(mx, sv); }
#pragma unroll
      for (int o2 = 8; o2; o2 >>= 1) mx = fmaxf(mx, __shfl_xor(mx, o2));
      const float mn = fmaxf(m_st[r], mx);
      const float alpha = __expf(m_st[r] - mn);
      float rs = 0.f;
#pragma unroll
      for (int j = 0; j < 4; ++j) { float p = __expf(s[j][r] - mn); pv[j][r] = p; rs += p; }
#pragma unroll
      for (int o2 = 8; o2; o2 >>= 1) rs += __shfl_xor(rs, o2);
      m_st[r] = mn;
      l_st[r] = l_st[r] * alpha + rs;
#pragma unroll
      for (int jd = 0; jd < 4; ++jd) o[jd][r] *= alpha;
#pragma unroll
      for (int j = 0; j < 4; ++j)
        Ks[(wv * 16 + quad * 4 + r) * 72 + j * 16 + l16] = f2b(pv[j][r]);
    }
    bf16x8 ap0 = *(const bf16x8*)(const void*)&Ks[(wv * 16 + l16) * 72 + quad * 8];
    bf16x8 ap1 = *(const bf16x8*)(const void*)&Ks[(wv * 16 + l16) * 72 + 32 + quad * 8];
#pragma unroll
    for (int jd = 0; jd < 4; ++jd) {
      bf16x8 bv0 = *(const bf16x8*)(const void*)&Vt[(jd * 16 + l16) * 72 + quad * 8];
      bf16x8 bv1 = *(const bf16x8*)(const void*)&Vt[(jd * 16 + l16) * 72 + 32 + quad * 8];
      o[jd] = __builtin_amdgcn_mfma_f32_16x16x32_bf16(ap0, bv0, o[jd], 0, 0, 0);
      o[jd] = __builtin_amdgcn_mfma_f32_16x16x32_bf16(ap1, bv1, o[jd], 0, 0, 0);
    }
  }
#pragma unroll
  for (int r = 0; r < 4; ++r) {
    const float inv = (l_st[r] > 0.f) ? 1.f / l_st[r] : 0.f;
#pragma unroll
    for (int jd = 0; jd < 4; ++jd)
      y[(size_t)(rowbase + quad * 4 + r) * 1024 + h * 64 + jd * 16 + l16] = f2b(o[jd][r] * inv);
  }
}

// ---------------------------------------------------------------------------
// Merged self-attention: blocks 0..511 star, 512..1023 hat. 1024 blocks x
// 36.9 KB LDS = 4 blocks/CU across 256 CUs. Hat body is STRAIGHT-LINE
// (R3 structure, 84 VGPR) — no branches around MFMA/softmax regions.
// ---------------------------------------------------------------------------
DEVI void star_body(unsigned short* Ks, unsigned short* Vt,
                    const unsigned short* qkv, const unsigned short* vT,
                    const unsigned long long* depb, unsigned short* y, int bid, int t) {
  const int tt = bid & 15, h = (bid >> 4) & 15, b = bid >> 8;
  const int wv = t >> 6, lane = t & 63;
  const int l16 = lane & 15, quad = lane >> 4;
  const int t0 = tt * 64;
  const int rowbase = b * 1024 + t0 + wv * 16;
  const unsigned short* qp = qkv + (size_t)(rowbase + l16) * 3072 + h * 64 + quad * 8;
  bf16x8 aq0 = *(const bf16x8*)(qp);
  bf16x8 aq1 = *(const bf16x8*)(qp + 32);
  const unsigned short* kb = qkv + (size_t)(b * 1024) * 3072 + 1024 + h * 64;
  const unsigned short* vb = vT + (size_t)(b * 16 + h) * 64 * 1024;
  float m_st[4] = {NEGINF, NEGINF, NEGINF, NEGINF};
  float l_st[4] = {0.f, 0.f, 0.f, 0.f};
  f32x4 o[4] = {};
  for (int ck = 0; ck <= tt; ++ck) {
    const int s0 = ck * 64;
    __syncthreads();
#pragma unroll
    for (int it = 0; it < 2; ++it) {
      int id = it * 256 + t; int row = id >> 3, g8 = (id & 7) * 8;
      *(uint4*)&Ks[row * 72 + g8] = *(const uint4*)(kb + (size_t)(s0 + row) * 3072 + g8);
      *(uint4*)&Vt[row * 72 + g8] = *(const uint4*)(vb + (size_t)row * 1024 + s0 + g8);
    }
    __syncthreads();
    unsigned long long dwv[4];
#pragma unroll
    for (int r = 0; r < 4; ++r)
      dwv[r] = depb[(size_t)(rowbase + quad * 4 + r) * 16 + ck];
    f32x4 s[4];
#pragma unroll
    for (int j = 0; j < 4; ++j) {
      bf16x8 bk0 = *(const bf16x8*)(const void*)&Ks[(j * 16 + l16) * 72 + quad * 8];
      bf16x8 bk1 = *(const bf16x8*)(const void*)&Ks[(j * 16 + l16) * 72 + 32 + quad * 8];
      f32x4 z = {};
      z = __builtin_amdgcn_mfma_f32_16x16x32_bf16(aq0, bk0, z, 0, 0, 0);
      z = __builtin_amdgcn_mfma_f32_16x16x32_bf16(aq1, bk1, z, 0, 0, 0);
      s[j] = z;
    }
    __syncthreads();
#pragma unroll
    for (int r = 0; r < 4; ++r) {
      const int trow = t0 + wv * 16 + quad * 4 + r;
      float mx = NEGINF;
#pragma unroll
      for (int j = 0; j < 4; ++j) {
        const int kg = s0 + j * 16 + l16;
        bool ok = (kg <= trow) && ((dwv[r] >> (j * 16 + l16)) & 1ull);
        float sv = ok ? s[j][r] * 0.125f : NEGINF;
        s[j][r] = sv;
        mx = fmaxf(mx, sv);
      }
#pragma unroll
      for (int o2 = 8; o2; o2 >>= 1) mx = fmaxf(mx, __shfl_xor(mx, o2));
      const float mn = fmaxf(m_st[r], mx);
      const bool dead = (mn == NEGINF);
      const float alpha = dead ? 1.f : __expf(m_st[r] - mn);
      float rs = 0.f;
#pragma unroll
      for (int j = 0; j < 4; ++j) {
        float p = dead ? 0.f : __expf(s[j][r] - mn);
        s[j][r] = p;
        rs += p;
      }
#pragma unroll
      for (int o2 = 8; o2; o2 >>= 1) rs += __shfl_xor(rs, o2);
      m_st[r] = mn;
      l_st[r] = l_st[r] * alpha + rs;
#pragma unroll
      for (int jd = 0; jd < 4; ++jd) o[jd][r] *= alpha;
#pragma unroll
      for (int j = 0; j < 4; ++j)
        Ks[(wv * 16 + quad * 4 + r) * 72 + j * 16 + l16] = f2b(s[j][r]);
    }
    bf16x8 ap0 = *(const bf16x8*)(const void*)&Ks[(wv * 16 + l16) * 72 + quad * 8];
    bf16x8 ap1 = *(const bf16x8*)(const void*)&Ks[(wv * 16 + l16) * 72 + 32 + quad * 8];
#pragma unroll
    for (int jd = 0; jd < 4; ++jd) {
      bf16x8 bv0 = *(const bf16x8*)(const void*)&Vt[(jd * 16 + l16) * 72 + quad * 8];
      bf16x8 bv1 = *(const bf16x8*)(const void*)&Vt[(jd * 16 + l16) * 72 + 32 + quad * 8];
      o[jd] = __builtin_amdgcn_mfma_f32_16x16x32_bf16(ap0, bv0, o[jd], 0, 0, 0);
      o[jd] = __builtin_amdgcn_mfma_f32_16x16x32_bf16(ap1, bv1, o[jd], 0, 0, 0);
    }
  }
#pragma unroll
  for (int r = 0; r < 4; ++r) {
    const float inv = (l_st[r] > 0.f) ? 1.f / l_st[r] : 0.f;
#pragma unroll
    for (int jd = 0; jd < 4; ++jd)
      y[(size_t)(rowbase + quad * 4 + r) * 1024 + h * 64 + jd * 16 + l16] = f2b(o[jd][r] * inv);
  }
}

DEVI void hat_body(unsigned short* Kst0, unsigned short* Vtt0,
                   const unsigned short* qkv,
                   const unsigned short* vsT, const unsigned short* vhT,
                   const unsigned long long* starb, const unsigned long long* hatb,
                   const unsigned long long* depb, const int* bflags,
                   unsigned short* y, int bid, int t) {
  unsigned short* Kst1 = Kst0 + 64 * 72;
  unsigned short* Vtt1 = Vtt0 + 64 * 72;
  unsigned short* Ps = Kst0;  // P overlay (16 rows x 136), K dead after QK
  const int tt = bid & 15, h = (bid >> 4) & 15, b = bid >> 8;
  const int wv = t >> 6, lane = t & 63;
  const int l16 = lane & 15, quad = lane >> 4;
  const int t0 = tt * 64;
  const int rowbase = b * 1024 + t0 + wv * 16;
  const unsigned short* qp = qkv + (size_t)(2048 + rowbase + l16) * 3072 + h * 64 + quad * 8;
  bf16x8 aq0 = *(const bf16x8*)(qp);
  bf16x8 aq1 = *(const bf16x8*)(qp + 32);
  const unsigned short* ksb = qkv + (size_t)(b * 1024) * 3072 + 1024 + h * 64;
  const unsigned short* khb = qkv + (size_t)(2048 + b * 1024) * 3072 + 1024 + h * 64;
  const unsigned short* vsb = vsT + (size_t)(b * 16 + h) * 65536;
  const unsigned short* vhb = vhT + (size_t)(b * 16 + h) * 65536;
  float m_st[4] = {NEGINF, NEGINF, NEGINF, NEGINF};
  float l_st[4] = {0.f, 0.f, 0.f, 0.f};
  f32x4 o[4] = {};
  for (int ck = 0; ck < 16; ++ck) {
    if (bflags[(b * 16 + tt) * 16 + ck] == 0) continue;  // block-uniform skip
    const int s0 = ck * 64;
    __syncthreads();
#pragma unroll
    for (int it = 0; it < 2; ++it) {  // unconditional: LDS always holds valid finite data
      int id = it * 256 + t; int row = id >> 3, g8 = (id & 7) * 8;
      *(uint4*)&Kst0[row * 72 + g8] = *(const uint4*)(ksb + (size_t)(s0 + row) * 3072 + g8);
      *(uint4*)&Kst1[row * 72 + g8] = *(const uint4*)(khb + (size_t)(s0 + row) * 3072 + g8);
      *(uint4*)&Vtt0[row * 72 + g8] = *(const uint4*)(vsb + (size_t)row * 1024 + s0 + g8);
      *(uint4*)&Vtt1[row * 72 + g8] = *(const uint4*)(vhb + (size_t)row * 1024 + s0 + g8);
    }
    __syncthreads();
    unsigned long long as_[4], ah_[4];
#pragma unroll
    for (int r = 0; r < 4; ++r) {
      const size_t mrow = (size_t)(rowbase + quad * 4 + r) * 16 + ck;
      const unsigned long long dw = depb[mrow];
      as_[r] = starb[mrow] & dw;
      ah_[r] = hatb[mrow] & dw;
    }
    f32x4 s[8];
#pragma unroll
    for (int j = 0; j < 8; ++j) {
      const unsigned short* kb = (j < 4) ? Kst0 : Kst1;
      const int row = (j & 3) * 16 + l16;
      bf16x8 bk0 = *(const bf16x8*)(const void*)&kb[row * 72 + quad * 8];
      bf16x8 bk1 = *(const bf16x8*)(const void*)&kb[row * 72 + 32 + quad * 8];
      f32x4 z = {};
      z = __builtin_amdgcn_mfma_f32_16x16x32_bf16(aq0, bk0, z, 0, 0, 0);
      z = __builtin_amdgcn_mfma_f32_16x16x32_bf16(aq1, bk1, z, 0, 0, 0);
      s[j] = z;
    }
    __syncthreads();  // K reads done before P overlay
#pragma unroll
    for (int r = 0; r < 4; ++r) {
      float mx = NEGINF;
#pragma unroll
      for (int j = 0; j < 8; ++j) {
        const int kl = (j & 3) * 16 + l16;
        const unsigned long long act = (j < 4) ? as_[r] : ah_[r];
        bool ok = ((act >> kl) & 1ull) != 0;
        float sv = ok ? s[j][r] * 0.125f : NEGINF;
        s[j][r] = sv;
        mx = fmaxf(mx, sv);
      }
#pragma unroll
      for (int o2 = 8; o2; o2 >>= 1) mx = fmaxf(mx, __shfl_xor(mx, o2));
      const float mn = fmaxf(m_st[r], mx);
      const bool dead = (mn == NEGINF);
      const float alpha = dead ? 1.f : __expf(m_st[r] - mn);
      float rs = 0.f;
#pragma unroll
      for (int j = 0; j < 8; ++j) {
        float p = dead ? 0.f : __expf(s[j][r] - mn);
        s[j][r] = p;
        rs += p;
      }
#pragma unroll
      for (int o2 = 8; o2; o2 >>= 1) rs += __shfl_xor(rs, o2);
      m_st[r] = mn;
      l_st[r] = l_st[r] * alpha + rs;
#pragma unroll
      for (int jd = 0; jd < 4; ++jd) o[jd][r] *= alpha;
#pragma unroll
      for (int j = 0; j < 8; ++j)
        Ps[(wv * 16 + quad * 4 + r) * 136 + j * 16 + l16] = f2b(s[j][r]);
    }
    // P wave-private: no barrier before readback
    bf16x8 ap[4];
#pragma unroll
    for (int kk = 0; kk < 4; ++kk)
      ap[kk] = *(const bf16x8*)(const void*)&Ps[(wv * 16 + l16) * 136 + kk * 32 + quad * 8];
#pragma unroll
    for (int jd = 0; jd < 4; ++jd) {
      bf16x8 bs0 = *(const bf16x8*)(const void*)&Vtt0[(jd * 16 + l16) * 72 + quad * 8];
      bf16x8 bs1 = *(const bf16x8*)(const void*)&Vtt0[(jd * 16 + l16) * 72 + 32 + quad * 8];
      bf16x8 bh0 = *(const bf16x8*)(const void*)&Vtt1[(jd * 16 + l16) * 72 + quad * 8];
      bf16x8 bh1 = *(const bf16x8*)(const void*)&Vtt1[(jd * 16 + l16) * 72 + 32 + quad * 8];
      o[jd] = __builtin_amdgcn_mfma_f32_16x16x32_bf16(ap[0], bs0, o[jd], 0, 0, 0);
      o[jd] = __builtin_amdgcn_mfma_f32_16x16x32_bf16(ap[1], bs1, o[jd], 0, 0, 0);
      o[jd] = __builtin_amdgcn_mfma_f32_16x16x32_bf16(ap[2], bh0, o[jd], 0, 0, 0);
      o[jd] = __builtin_amdgcn_mfma_f32_16x16x32_bf16(ap[3], bh1, o[jd], 0, 0, 0);
    }
  }
#pragma unroll
  for (int r = 0; r < 4; ++r) {
    const float inv = (l_st[r] > 0.f) ? 1.f / l_st[r] : 0.f;
#pragma unroll
    for (int jd = 0; jd < 4; ++jd)
      y[(size_t)(2048 + rowbase + quad * 4 + r) * 1024 + h * 64 + jd * 16 + l16] = f2b(o[jd][r] * inv);
  }
}

__global__ __launch_bounds__(256) void self_attn_mfma(
    const unsigned short* __restrict__ qkv,
    const unsigned short* __restrict__ vstT, const unsigned short* __restrict__ vhtT,
    const unsigned long long* __restrict__ sbits, const unsigned long long* __restrict__ hbits,
    const unsigned long long* __restrict__ dbits, const int* __restrict__ bflags,
    unsigned short* __restrict__ y) {
  __shared__ __attribute__((aligned(16))) unsigned short Kbuf[2][64 * 72];
  __shared__ __attribute__((aligned(16))) unsigned short Vbuf[2][64 * 72];
  const int bid = blockIdx.x;
  const int t = threadIdx.x;
  if (bid < 512) {
    star_body(&Kbuf[0][0], &Vbuf[0][0], qkv, vstT, dbits, y, bid, t);
  } else {
    hat_body(&Kbuf[0][0], &Vbuf[0][0], qkv, vstT, vhtT, sbits, hbits, dbits, bflags, y, bid - 512, t);
  }
}

// ---------------------------------------------------------------------------
extern "C" void kernel_launch(void* const* d_in, const int* in_sizes, int n_in,
                              void* d_out, int out_size, void* d_ws, size_t ws_size,
                              hipStream_t stream) {
  const void* xs = d_in[0];
  const void* xh = d_in[1];
  const void* cc = d_in[2];
  const void* mstar = d_in[3];
  const void* mhat = d_in[4];
  const void* mdep = d_in[5];
  const void* ng = d_in[6];
  const void* nb = d_in[7];
  const void* Wq = d_in[8];
  const void* bq = d_in[9];
  const void* Wkv = d_in[10];
  const void* bkv = d_in[11];
  const void* Wco = d_in[12];
  const void* bco = d_in[13];
  const void* Wada = d_in[14];
  const void* bada = d_in[15];
  const void* Wqkv = d_in[16];
  const void* bqkv = d_in[17];
  const void* Wo = d_in[18];
  const void* bo = d_in[19];
  const void* W1 = d_in[20];
  const void* b1 = d_in[21];
  const void* W2 = d_in[22];
  const void* b2 = d_in[23];
  (void)in_sizes; (void)n_in; (void)out_size; (void)ws_size;

  char* ws = (char*)d_ws;
  size_t off = 0;
  auto alloc = [&](size_t bytes) -> char* {
    char* p = ws + off;
    off += (bytes + 255) & ~(size_t)255;
    return p;
  };
  int* flags = (int*)alloc(256);
  int* bflags = (int*)alloc(512 * 4);
  unsigned short* smallb = (unsigned short*)alloc(21504 * 2);
  unsigned short* ngb = smallb, *nbb = smallb + 1024, *bqb = smallb + 2048,
      *bkvb = smallb + 3072, *bcob = smallb + 5120, *badab = smallb + 6144,
      *bqkvb = smallb + 12288, *bob = smallb + 15360, *b1b = smallb + 16384,
      *b2b = smallb + 20480;
  unsigned short* WqT = (unsigned short*)alloc(1048576ull * 2);
  unsigned short* WkvT = (unsigned short*)alloc(2097152ull * 2);
  unsigned short* WcoT = (unsigned short*)alloc(1048576ull * 2);
  unsigned short* WadaT = (unsigned short*)alloc(6291456ull * 2);
  unsigned short* WqkvT = (unsigned short*)alloc(3145728ull * 2);
  unsigned short* WoT = (unsigned short*)alloc(1048576ull * 2);
  unsigned short* W1T = (unsigned short*)alloc(4194304ull * 2);
  unsigned short* W2T = (unsigned short*)alloc(4194304ull * 2);
  unsigned short* xsb = (unsigned short*)alloc(2097152ull * 2);
  unsigned short* xhb = (unsigned short*)alloc(2097152ull * 2);
  unsigned short* xn = (unsigned short*)alloc(4194304ull * 2);
  unsigned short* qb = (unsigned short*)alloc(4194304ull * 2);
  unsigned short* kvb = (unsigned short*)alloc(1048576ull * 2);
  unsigned short* gada = (unsigned short*)alloc(25165824ull * 2);
  unsigned short* msb = (unsigned short*)alloc(4194304ull * 2);
  unsigned short* qkvb = (unsigned short*)alloc(12582912ull * 2);
  float* x1 = (float*)alloc(4194304ull * 4);
  unsigned short* hid = (unsigned short*)alloc(16777216ull * 2);
  unsigned long long* mb = (unsigned long long*)alloc(3ull * 32768 * 8);
  unsigned short* kvT = (unsigned short*)alloc(524288ull * 2);
  unsigned short* vstT = (unsigned short*)alloc(2097152ull * 2);
  unsigned short* vhtT = (unsigned short*)alloc(2097152ull * 2);

  unsigned long long* sbits = mb;
  unsigned long long* hbits = mb + 32768;
  unsigned long long* dbits = mb + 65536;
  unsigned short* ccb = hid;              // dead before hid written
  unsigned short* lnx = hid + 1048576;    // dead before hid written
  unsigned short* yca = xn;
  unsigned short* silub = qb;
  unsigned short* yat = msb;

  dim3 blk(256);
  detect_flags<<<1, blk, 0, stream>>>((const unsigned int*)xs, (const unsigned int*)mdep, flags);

  cvt_bf16<<<2048, blk, 0, stream>>>(xs, xsb, 2097152, flags);
  cvt_bf16<<<2048, blk, 0, stream>>>(xh, xhb, 2097152, flags);
  cvt_bf16<<<512, blk, 0, stream>>>(cc, ccb, 524288, flags);
  P10 ps10; ps10.p[0] = ng; ps10.p[1] = nb; ps10.p[2] = bq; ps10.p[3] = bkv;
  ps10.p[4] = bco; ps10.p[5] = bada; ps10.p[6] = bqkv; ps10.p[7] = bo;
  ps10.p[8] = b1; ps10.p[9] = b2;
  cvt_small<<<84, blk, 0, stream>>>(ps10, smallb, flags);

  transpose_cvt<<<dim3(32, 32), blk, 0, stream>>>(Wq, WqT, 1024, 1024, flags);
  transpose_cvt<<<dim3(32, 64), blk, 0, stream>>>(Wkv, WkvT, 1024, 2048, flags);
  transpose_cvt<<<dim3(32, 32), blk, 0, stream>>>(Wco, WcoT, 1024, 1024, flags);
  transpose_cvt<<<dim3(32, 192), blk, 0, stream>>>(Wada, WadaT, 1024, 6144, flags);
  transpose_cvt<<<dim3(32, 96), blk, 0, stream>>>(Wqkv, WqkvT, 1024, 3072, flags);
  transpose_cvt<<<dim3(32, 32), blk, 0, stream>>>(Wo, WoT, 1024, 1024, flags);
  transpose_cvt<<<dim3(32, 128), blk, 0, stream>>>(W1, W1T, 1024, 4096, flags);
  transpose_cvt<<<dim3(128, 32), blk, 0, stream>>>(W2, W2T, 4096, 1024, flags);

  P3 ps3; ps3.p[0] = mstar; ps3.p[1] = mhat; ps3.p[2] = mdep;
  pack_mask3<<<dim3(512, 3), blk, 0, stream>>>(ps3, mb, flags);
  hat_blockflags<<<32, blk, 0, stream>>>(sbits, hbits, bflags);

  ln_affine<<<4096, blk, 0, stream>>>(xsb, xhb, ngb, nbb, lnx, xn);
  gemm_bt<EPI_BF16><<<dim3(32, 8), blk, 0, stream>>>(xn, WqT, bqb, qb, 4096, 1024, 1024, nullptr, nullptr, nullptr, nullptr);
  gemm_bt<EPI_BF16><<<dim3(4, 16), blk, 0, stream>>>(ccb, WkvT, bkvb, kvb, 512, 2048, 1024, nullptr, nullptr, nullptr, nullptr);
  vtrans<<<dim3(4, 32), blk, 0, stream>>>(kvb, kvT, 256, 2048, 1024, 0);
  cross_attn_mfma<<<1024, blk, 0, stream>>>(qb, kvb, kvT, yca);
  gemm_bt<EPI_SILU><<<dim3(32, 8), blk, 0, stream>>>(yca, WcoT, bcob, silub, 4096, 1024, 1024, nullptr, nullptr, nullptr, nullptr);
  gemm_bt<EPI_BF16><<<dim3(32, 48), blk, 0, stream>>>(silub, WadaT, badab, gada, 4096, 6144, 1024, nullptr, nullptr, nullptr, nullptr);
  mod_ms<<<4096, blk, 0, stream>>>(lnx, gada, msb);
  gemm_bt<EPI_BF16><<<dim3(32, 24), blk, 0, stream>>>(msb, WqkvT, bqkvb, qkvb, 4096, 3072, 1024, nullptr, nullptr, nullptr, nullptr);
  vtrans<<<dim3(16, 32), blk, 0, stream>>>(qkvb, vstT, 1024, 3072, 2048, 0);
  vtrans<<<dim3(16, 32), blk, 0, stream>>>(qkvb, vhtT, 1024, 3072, 2048, 2048);
  self_attn_mfma<<<1024, blk, 0, stream>>>(qkvb, vstT, vhtT, sbits, hbits, dbits, bflags, yat);
  gemm_bt<EPI_GATE_XRES><<<dim3(32, 8), blk, 0, stream>>>(yat, WoT, bob, x1, 4096, 1024, 1024, gada + 2048, xsb, xhb, nullptr);
  ln_mod<<<4096, blk, 0, stream>>>(x1, gada, msb);
  gemm_bt<EPI_GELU><<<dim3(32, 32), blk, 0, stream>>>(msb, W1T, b1b, hid, 4096, 4096, 1024, nullptr, nullptr, nullptr, nullptr);
  gemm_bt<EPI_GATE_OUT><<<dim3(32, 8), blk, 0, stream>>>(hid, W2T, b2b, d_out, 4096, 1024, 4096, gada + 5120, x1, nullptr, flags);
}

// Round 7
// 782.397 us; speedup vs baseline: 1.2143x; 1.0306x over previous
//
#include <hip/hip_runtime.h>
#include <hip/hip_bf16.h>
#include <stdint.h>

#define DEVI __device__ __forceinline__

typedef __bf16 bf16x8 __attribute__((ext_vector_type(8)));
typedef float f32x4 __attribute__((ext_vector_type(4)));
typedef unsigned short us;
typedef unsigned long long ull;

DEVI float b2f(us u) { union { unsigned int i; float f; } v; v.i = ((unsigned int)u) << 16; return v.f; }
DEVI us f2b(float f) {
  union { unsigned int i; float f; } v; v.f = f;
  unsigned int r = (v.i + 0x7fffu + ((v.i >> 16) & 1u)) >> 16;
  return (us)r;
}

#define NEGINF (-__builtin_inff())

DEVI void gl2lds16(const us* g, us* l) {
  __builtin_amdgcn_global_load_lds(
      (const __attribute__((address_space(1))) unsigned int*)g,
      (__attribute__((address_space(3))) unsigned int*)l, 16, 0, 0);
}

// ---------------------------------------------------------------------------
// Runtime dtype detection. flags[0]: f32 inputs; flags[1]: byte-packed masks.
// ---------------------------------------------------------------------------
__global__ __launch_bounds__(256) void detect_flags(
    const unsigned int* __restrict__ xw, const unsigned int* __restrict__ mw,
    int* __restrict__ flags) {
  const int t = threadIdx.x;
  int cnt = 0, big = 0;
  for (int i = t; i < 4096; i += 256) {
    unsigned int w = xw[i];
    us lo = (us)(w & 0xffffu);
    float a = fabsf(b2f(lo));
    cnt += ((lo == 0) || (a >= 1e-8f && a <= 256.f)) ? 1 : 0;
    big |= (mw[i] > 1u) ? 1 : 0;
  }
  for (int o = 32; o; o >>= 1) { cnt += __shfl_down(cnt, o); big |= __shfl_down(big, o); }
  __shared__ int sc[4], sb[4];
  if ((t & 63) == 0) { sc[t >> 6] = cnt; sb[t >> 6] = big; }
  __syncthreads();
  if (t == 0) {
    flags[0] = (sc[0] + sc[1] + sc[2] + sc[3] < 2048) ? 1 : 0;
    flags[1] = (sb[0] | sb[1] | sb[2] | sb[3]);
  }
}

__global__ __launch_bounds__(256) void cvt_bf16(
    const void* __restrict__ src, us* __restrict__ dst, int n,
    const int* __restrict__ flags) {
  const int f32mode = flags[0];
  int idx = (blockIdx.x * 256 + threadIdx.x) * 4;
  if (idx >= n) return;
  if (f32mode) {
    const float* s = (const float*)src;
    float4 v = *(const float4*)(s + idx);
    dst[idx] = f2b(v.x); dst[idx + 1] = f2b(v.y);
    dst[idx + 2] = f2b(v.z); dst[idx + 3] = f2b(v.w);
  } else {
    *(uint2*)(dst + idx) = *(const uint2*)((const us*)src + idx);
  }
}

struct P10 { const void* p[10]; };
__global__ __launch_bounds__(256) void cvt_small(P10 ps, us* __restrict__ dst,
                                                 const int* __restrict__ flags) {
  const int offs[11] = {0, 1024, 2048, 3072, 5120, 6144, 12288, 15360, 16384, 20480, 21504};
  int idx = blockIdx.x * 256 + threadIdx.x;
  if (idx >= 21504) return;
  int seg = 0;
#pragma unroll
  for (int i = 1; i < 10; ++i) seg += (idx >= offs[i]) ? 1 : 0;
  int local = idx - offs[seg];
  float v = flags[0] ? ((const float*)ps.p[seg])[local]
                     : b2f(((const us*)ps.p[seg])[local]);
  dst[idx] = f2b(v);
}

// Vectorized 64x64 convert+transpose: W (K,N) f32/bf16 -> WT (N,K) bf16.
// XOR-16 column swizzle in LDS -> conflict-free column gather.
__global__ __launch_bounds__(256) void transpose_cvt64(
    const void* __restrict__ W, us* __restrict__ WT, int K, int N,
    const int* __restrict__ flags) {
  __shared__ __attribute__((aligned(16))) us tile[64 * 72];
  const int f32m = flags[0];
  const int k0 = blockIdx.x * 64, n0 = blockIdx.y * 64;
  const int t = threadIdx.x;
  const int row = t >> 2, colb = (t & 3) * 16;
  const int sw = ((row >> 4) & 3) << 4;
  us tmp[16];
  if (f32m) {
    const float* src = (const float*)W + (size_t)(k0 + row) * N + n0 + colb;
#pragma unroll
    for (int i = 0; i < 16; i += 4) {
      float4 v = *(const float4*)(src + i);
      tmp[i] = f2b(v.x); tmp[i + 1] = f2b(v.y); tmp[i + 2] = f2b(v.z); tmp[i + 3] = f2b(v.w);
    }
  } else {
    const us* src = (const us*)W + (size_t)(k0 + row) * N + n0 + colb;
    *(uint4*)tmp = *(const uint4*)src;
    *(uint4*)(tmp + 8) = *(const uint4*)(src + 8);
  }
  *(uint4*)&tile[row * 72 + (colb ^ sw)] = *(uint4*)tmp;
  *(uint4*)&tile[row * 72 + (colb ^ sw) + 8] = *(uint4*)(tmp + 8);
  __syncthreads();
  const int orow = t >> 2, ocolb = (t & 3) * 16;
  const int pc = (orow & 15) | ((orow & 48) ^ (ocolb & 48));
  us out[16];
#pragma unroll
  for (int i = 0; i < 16; ++i) out[i] = tile[(ocolb + i) * 72 + pc];
  us* dst = WT + (size_t)(n0 + orow) * K + k0 + ocolb;
  *(uint4*)dst = *(uint4*)out;
  *(uint4*)(dst + 8) = *(uint4*)(out + 8);
}

struct P3 { const void* p[3]; };
__global__ __launch_bounds__(256) void pack_mask3(P3 ms, ull* __restrict__ bits,
                                                  const int* __restrict__ flags) {
  const int bytemode = flags[1];
  const void* m = ms.p[blockIdx.y];
  ull* out = bits + (size_t)blockIdx.y * 32768;
  int wv = blockIdx.x * 4 + (threadIdx.x >> 6);
  int lane = threadIdx.x & 63;
  for (int w = 0; w < 16; ++w) {
    int v;
    if (bytemode) v = ((const unsigned char*)m)[(size_t)wv * 1024 + w * 64 + lane];
    else          v = ((const int*)m)[(size_t)wv * 1024 + w * 64 + lane];
    ull b = __ballot(v != 0);
    if (lane == 0) out[(size_t)wv * 16 + w] = b;
  }
}

__global__ __launch_bounds__(256) void hat_blockflags(
    const ull* __restrict__ starb, const ull* __restrict__ hatb, int* __restrict__ bf) {
  const int bt = blockIdx.x;
  const int b = bt >> 4, tt = bt & 15;
  const int t = threadIdx.x, wv = t >> 6, lane = t & 63;
  const int t0 = tt * 64;
  for (int k = 0; k < 4; ++k) {
    int ck = wv * 4 + k;
    ull sw = starb[(size_t)(b * 1024 + t0 + lane) * 16 + ck];
    ull hw = hatb[(size_t)(b * 1024 + t0 + lane) * 16 + ck];
    int f = (__ballot(sw != 0ull) ? 1 : 0) | (__ballot(hw != 0ull) ? 2 : 0);
    if (lane == 0) bf[bt * 16 + ck] = f;
  }
}

// V transpose to [bh][64(d)][T]
__global__ __launch_bounds__(256) void vtrans(
    const us* __restrict__ src, us* __restrict__ dst,
    int T, int stride, int colBase, int rowOff) {
  __shared__ __attribute__((aligned(16))) us tile[64][65];
  const int bh = blockIdx.y, b = bh >> 4, h = bh & 15;
  const int t0 = blockIdx.x * 64;
  const int t = threadIdx.x;
#pragma unroll
  for (int it = 0; it < 2; ++it) {
    int idx = it * 256 + t; int r = idx >> 3, c8 = (idx & 7) * 8;
    uint4 d4 = *(const uint4*)(src + (size_t)(rowOff + b * T + t0 + r) * stride + colBase + h * 64 + c8);
    const us* e = (const us*)&d4;
#pragma unroll
    for (int i = 0; i < 8; ++i) tile[r][c8 + i] = e[i];
  }
  __syncthreads();
#pragma unroll
  for (int it = 0; it < 2; ++it) {
    int idx = it * 256 + t; int d = idx >> 3, c8 = (idx & 7) * 8;
    us tmp[8];
#pragma unroll
    for (int i = 0; i < 8; ++i) tmp[i] = tile[c8 + i][d];
    *(uint4*)(dst + ((size_t)(bh * 64 + d)) * T + t0 + c8) = *(const uint4*)tmp;
  }
}

// ---------------------------------------------------------------------------
// LayerNorm + modulation (ln_affine reads raw input via flag branch)
// ---------------------------------------------------------------------------
__global__ __launch_bounds__(256) void ln_affine(
    const void* __restrict__ xs, const void* __restrict__ xh,
    const us* __restrict__ gw, const us* __restrict__ bw,
    us* __restrict__ lnx, us* __restrict__ xn, const int* __restrict__ flags) {
  const int f32m = flags[0];
  const int row = blockIdx.x;
  const void* xp = (row < 2048) ? xs : xh;
  const size_t base = (size_t)(row & 2047) * 1024;
  const int t = threadIdx.x;
  float v[4]; float s = 0.f, ss = 0.f;
#pragma unroll
  for (int i = 0; i < 4; ++i) {
    size_t idx = base + i * 256 + t;
    float x = f32m ? ((const float*)xp)[idx] : b2f(((const us*)xp)[idx]);
    v[i] = x; s += x; ss += x * x;
  }
  for (int o = 32; o; o >>= 1) { s += __shfl_down(s, o); ss += __shfl_down(ss, o); }
  __shared__ float red[2][4];
  const int wv = t >> 6, lane = t & 63;
  if (lane == 0) { red[0][wv] = s; red[1][wv] = ss; }
  __syncthreads();
  s = red[0][0] + red[0][1] + red[0][2] + red[0][3];
  ss = red[1][0] + red[1][1] + red[1][2] + red[1][3];
  const float mean = s * (1.f / 1024.f);
  const float var = fmaxf(ss * (1.f / 1024.f) - mean * mean, 0.f);
  const float rstd = rsqrtf(var + 1e-6f);
  const size_t ro = (size_t)row * 1024;
#pragma unroll
  for (int i = 0; i < 4; ++i) {
    int c = i * 256 + t;
    float n = (v[i] - mean) * rstd;
    lnx[ro + c] = f2b(n);
    xn[ro + c] = f2b(n * b2f(gw[c]) + b2f(bw[c]));
  }
}

__global__ __launch_bounds__(256) void mod_ms(
    const us* __restrict__ lnx, const us* __restrict__ gada, us* __restrict__ ms) {
  const size_t idx = ((size_t)blockIdx.x * 256 + threadIdx.x) * 4;
  const int row = (int)(idx >> 10), c = (int)(idx & 1023);
  const size_t gb = (size_t)row * 6144;
#pragma unroll
  for (int i = 0; i < 4; ++i) {
    float sh = b2f(gada[gb + c + i]);
    float sc = b2f(gada[gb + 1024 + c + i]);
    ms[idx + i] = f2b(b2f(lnx[idx + i]) * (1.f + sc) + sh);
  }
}

__global__ __launch_bounds__(256) void ln_mod(
    const float* __restrict__ x1, const us* __restrict__ gada, us* __restrict__ m2) {
  const int row = blockIdx.x;
  const float* xp = x1 + (size_t)row * 1024;
  const int t = threadIdx.x;
  float v[4]; float s = 0.f, ss = 0.f;
#pragma unroll
  for (int i = 0; i < 4; ++i) { float x = xp[i * 256 + t]; v[i] = x; s += x; ss += x * x; }
  for (int o = 32; o; o >>= 1) { s += __shfl_down(s, o); ss += __shfl_down(ss, o); }
  __shared__ float red[2][4];
  const int wv = t >> 6, lane = t & 63;
  if (lane == 0) { red[0][wv] = s; red[1][wv] = ss; }
  __syncthreads();
  s = red[0][0] + red[0][1] + red[0][2] + red[0][3];
  ss = red[1][0] + red[1][1] + red[1][2] + red[1][3];
  const float mean = s * (1.f / 1024.f);
  const float var = fmaxf(ss * (1.f / 1024.f) - mean * mean, 0.f);
  const float rstd = rsqrtf(var + 1e-6f);
  const size_t gb = (size_t)row * 6144;
#pragma unroll
  for (int i = 0; i < 4; ++i) {
    int c = i * 256 + t;
    float n = (v[i] - mean) * rstd;
    float sh = b2f(gada[gb + 3072 + c]);
    float sc = b2f(gada[gb + 4096 + c]);
    m2[(size_t)row * 1024 + c] = f2b(n * (1.f + sc) + sh);
  }
}

// ---------------------------------------------------------------------------
// MFMA GEMM, m97-style global_load_lds staging.
// ---------------------------------------------------------------------------
enum { EPI_BF16 = 0, EPI_SILU, EPI_GELU, EPI_GATE_XRES, EPI_GATE_OUT };

template <int EPI>
__global__ __launch_bounds__(256) void gemm_bt(
    const us* __restrict__ A, const us* __restrict__ BT,
    const us* __restrict__ bias, void* __restrict__ out,
    int M, int N, int K,
    const us* __restrict__ gate,
    const void* __restrict__ res0, const void* __restrict__ res1,
    const int* __restrict__ oflags) {
  __shared__ __attribute__((aligned(16))) us As[128 * 32];
  __shared__ __attribute__((aligned(16))) us Bs[128 * 32];
  const int m0 = blockIdx.x * 128, n0 = blockIdx.y * 128;
  const int t = threadIdx.x;
  const int wave = t >> 6, lane = t & 63;
  const int wm = (wave >> 1) * 64, wn = (wave & 1) * 64;
  const int l16 = lane & 15, quad = lane >> 4;
  f32x4 acc[4][4] = {};

  const int lr = lane >> 2, lc = (lane & 3) * 8;
  const us* gA = A + (size_t)(m0 + wave * 32 + lr) * K + lc;
  const us* gB = BT + (size_t)(n0 + wave * 32 + lr) * K + lc;
  us* lA = &As[wave * 32 * 32];
  us* lB = &Bs[wave * 32 * 32];

  for (int k0 = 0; k0 < K; k0 += 32) {
    __syncthreads();
    gl2lds16(gA + k0, lA);
    gl2lds16(gA + (size_t)16 * K + k0, lA + 512);
    gl2lds16(gB + k0, lB);
    gl2lds16(gB + (size_t)16 * K + k0, lB + 512);
    __syncthreads();
    bf16x8 af[4], bf[4];
#pragma unroll
    for (int i = 0; i < 4; ++i) af[i] = *(const bf16x8*)(const void*)&As[(wm + i * 16 + l16) * 32 + quad * 8];
#pragma unroll
    for (int j = 0; j < 4; ++j) bf[j] = *(const bf16x8*)(const void*)&Bs[(wn + j * 16 + l16) * 32 + quad * 8];
#pragma unroll
    for (int i = 0; i < 4; ++i)
#pragma unroll
      for (int j = 0; j < 4; ++j)
        acc[i][j] = __builtin_amdgcn_mfma_f32_16x16x32_bf16(af[i], bf[j], acc[i][j], 0, 0, 0);
  }

#pragma unroll
  for (int i = 0; i < 4; ++i) {
    const int gm = m0 + wm + i * 16 + quad * 4;
#pragma unroll
    for (int j = 0; j < 4; ++j) {
      const int gn = n0 + wn + j * 16 + l16;
      const float bv = b2f(bias[gn]);
#pragma unroll
      for (int r = 0; r < 4; ++r) {
        const int gmr = gm + r;
        float v = acc[i][j][r] + bv;
        const size_t oi = (size_t)gmr * N + gn;
        if constexpr (EPI == EPI_BF16) {
          ((us*)out)[oi] = f2b(v);
        } else if constexpr (EPI == EPI_SILU) {
          ((us*)out)[oi] = f2b(v / (1.f + __expf(-v)));
        } else if constexpr (EPI == EPI_GELU) {
          float u = 0.7978845608028654f * (v + 0.044715f * v * v * v);
          float th = 1.f - 2.f / (__expf(2.f * u) + 1.f);
          ((us*)out)[oi] = f2b(0.5f * v * (1.f + th));
        } else if constexpr (EPI == EPI_GATE_XRES) {
          float g = b2f(gate[(size_t)gmr * 6144 + gn]);
          const void* xr = (gmr < 2048) ? res0 : res1;
          size_t xi = (size_t)(gmr & 2047) * 1024 + gn;
          float x = oflags[0] ? ((const float*)xr)[xi] : b2f(((const us*)xr)[xi]);
          ((float*)out)[oi] = x + g * v;
        } else {
          float g = b2f(gate[(size_t)gmr * 6144 + gn]);
          float x = ((const float*)res0)[oi];
          float r2 = x + g * v;
          if (oflags[0]) ((float*)out)[oi] = r2;
          else ((us*)out)[oi] = f2b(r2);
        }
      }
    }
  }
}

// ---------------------------------------------------------------------------
// MFMA flash attention, 128-key staging rounds, XCD-locality swizzled grids.
// LDS: K[2][64*72] + V[2][64*72] = 36.9 KB; P (16x136/wave) overlays K.
// ---------------------------------------------------------------------------

// Cross: 256 keys = 2 rounds of 128; no masks.
__global__ __launch_bounds__(256) void cross_attn_mfma(
    const us* __restrict__ q, const us* __restrict__ kv,
    const us* __restrict__ vT, us* __restrict__ y) {
  __shared__ __attribute__((aligned(16))) us Kb[2][64 * 72];
  __shared__ __attribute__((aligned(16))) us Vb[2][64 * 72];
  us* Ps = &Kb[0][0];
  const int bid = blockIdx.x;
  const int xcd = bid & 7, tmp = bid >> 3;
  const int tt = tmp & 15, gq = tmp >> 4;
  const int g = gq * 8 + xcd;          // (st,b,h) group
  const int st = g >> 5, b = (g >> 4) & 1, h = g & 15;
  const int t = threadIdx.x, wv = t >> 6, lane = t & 63;
  const int l16 = lane & 15, quad = lane >> 4;
  const int rowbase = st * 2048 + b * 1024 + tt * 64 + wv * 16;
  const us* qp = q + (size_t)(rowbase + l16) * 1024 + h * 64 + quad * 8;
  bf16x8 aq0 = *(const bf16x8*)(qp);
  bf16x8 aq1 = *(const bf16x8*)(qp + 32);
  const us* kb = kv + (size_t)b * (256 * 2048) + h * 64;
  const us* vb = vT + (size_t)(b * 16 + h) * 64 * 256;
  float m_st[4] = {NEGINF, NEGINF, NEGINF, NEGINF};
  float l_st[4] = {0.f, 0.f, 0.f, 0.f};
  f32x4 o[4] = {};
  for (int rnd = 0; rnd < 2; ++rnd) {
    const int s0 = rnd * 128;
    __syncthreads();
#pragma unroll
    for (int it = 0; it < 2; ++it) {
      int id = it * 256 + t; int row = id >> 3, g8 = (id & 7) * 8;
      *(uint4*)&Kb[0][row * 72 + g8] = *(const uint4*)(kb + (size_t)(s0 + row) * 2048 + g8);
      *(uint4*)&Kb[1][row * 72 + g8] = *(const uint4*)(kb + (size_t)(s0 + 64 + row) * 2048 + g8);
      *(uint4*)&Vb[0][row * 72 + g8] = *(const uint4*)(vb + (size_t)row * 256 + s0 + g8);
      *(uint4*)&Vb[1][row * 72 + g8] = *(const uint4*)(vb + (size_t)row * 256 + s0 + 64 + g8);
    }
    __syncthreads();
    f32x4 s[8];
#pragma unroll
    for (int j = 0; j < 8; ++j) {
      const us* kbuf = (j < 4) ? &Kb[0][0] : &Kb[1][0];
      const int row = (j & 3) * 16 + l16;
      bf16x8 bk0 = *(const bf16x8*)(const void*)&kbuf[row * 72 + quad * 8];
      bf16x8 bk1 = *(const bf16x8*)(const void*)&kbuf[row * 72 + 32 + quad * 8];
      f32x4 z = {};
      z = __builtin_amdgcn_mfma_f32_16x16x32_bf16(aq0, bk0, z, 0, 0, 0);
      z = __builtin_amdgcn_mfma_f32_16x16x32_bf16(aq1, bk1, z, 0, 0, 0);
      s[j] = z;
    }
    __syncthreads();
#pragma unroll
    for (int r = 0; r < 4; ++r) {
      float mx = NEGINF;
#pragma unroll
      for (int j = 0; j < 8; ++j) { float sv = s[j][r] * 0.125f; s[j][r] = sv; mx = fmaxf(mx, sv); }
#pragma unroll
      for (int o2 = 8; o2; o2 >>= 1) mx = fmaxf(mx, __shfl_xor(mx, o2));
      const float mn = fmaxf(m_st[r], mx);
      const float alpha = __expf(m_st[r] - mn);
      float rs = 0.f;
#pragma unroll
      for (int j = 0; j < 8; ++j) { float p = __expf(s[j][r] - mn); s[j][r] = p; rs += p; }
#pragma unroll
      for (int o2 = 8; o2; o2 >>= 1) rs += __shfl_xor(rs, o2);
      m_st[r] = mn;
      l_st[r] = l_st[r] * alpha + rs;
#pragma unroll
      for (int jd = 0; jd < 4; ++jd) o[jd][r] *= alpha;
#pragma unroll
      for (int j = 0; j < 8; ++j)
        Ps[(wv * 16 + quad * 4 + r) * 136 + j * 16 + l16] = f2b(s[j][r]);
    }
    bf16x8 ap[4];
#pragma unroll
    for (int kk = 0; kk < 4; ++kk)
      ap[kk] = *(const bf16x8*)(const void*)&Ps[(wv * 16 + l16) * 136 + kk * 32 + quad * 8];
#pragma unroll
    for (int jd = 0; jd < 4; ++jd) {
      bf16x8 b0 = *(const bf16x8*)(const void*)&Vb[0][(jd * 16 + l16) * 72 + quad * 8];
      bf16x8 b1 = *(const bf16x8*)(const void*)&Vb[0][(jd * 16 + l16) * 72 + 32 + quad * 8];
      bf16x8 b2 = *(const bf16x8*)(const void*)&Vb[1][(jd * 16 + l16) * 72 + quad * 8];
      bf16x8 b3 = *(const bf16x8*)(const void*)&Vb[1][(jd * 16 + l16) * 72 + 32 + quad * 8];
      o[jd] = __builtin_amdgcn_mfma_f32_16x16x32_bf16(ap[0], b0, o[jd], 0, 0, 0);
      o[jd] = __builtin_amdgcn_mfma_f32_16x16x32_bf16(ap[1], b1, o[jd], 0, 0, 0);
      o[jd] = __builtin_amdgcn_mfma_f32_16x16x32_bf16(ap[2], b2, o[jd], 0, 0, 0);
      o[jd] = __builtin_amdgcn_mfma_f32_16x16x32_bf16(ap[3], b3, o[jd], 0, 0, 0);
    }
  }
#pragma unroll
  for (int r = 0; r < 4; ++r) {
    const float inv = (l_st[r] > 0.f) ? 1.f / l_st[r] : 0.f;
#pragma unroll
    for (int jd = 0; jd < 4; ++jd)
      y[(size_t)(rowbase + quad * 4 + r) * 1024 + h * 64 + jd * 16 + l16] = f2b(o[jd][r] * inv);
  }
}

// Star: paired chunks (128 keys/round), causal+dep.
DEVI void star_body(us* Ks0, us* Vt0, const us* qkv, const us* vT,
                    const ull* depb, us* y, int b, int h, int tt, int t) {
  us* Ks1 = Ks0 + 64 * 72;
  us* Vt1 = Vt0 + 64 * 72;
  us* Ps = Ks0;
  const int wv = t >> 6, lane = t & 63;
  const int l16 = lane & 15, quad = lane >> 4;
  const int t0 = tt * 64;
  const int rowbase = b * 1024 + t0 + wv * 16;
  const us* qp = qkv + (size_t)(rowbase + l16) * 3072 + h * 64 + quad * 8;
  bf16x8 aq0 = *(const bf16x8*)(qp);
  bf16x8 aq1 = *(const bf16x8*)(qp + 32);
  const us* kb = qkv + (size_t)(b * 1024) * 3072 + 1024 + h * 64;
  const us* vb = vT + (size_t)(b * 16 + h) * 65536;
  float m_st[4] = {NEGINF, NEGINF, NEGINF, NEGINF};
  float l_st[4] = {0.f, 0.f, 0.f, 0.f};
  f32x4 o[4] = {};
  for (int ck0 = 0; ck0 <= tt; ck0 += 2) {
    const int s0 = ck0 * 64;  // pair covers keys s0..s0+127 (chunk ck0+1 <= 15 always)
    __syncthreads();
#pragma unroll
    for (int it = 0; it < 2; ++it) {
      int id = it * 256 + t; int row = id >> 3, g8 = (id & 7) * 8;
      *(uint4*)&Ks0[row * 72 + g8] = *(const uint4*)(kb + (size_t)(s0 + row) * 3072 + g8);
      *(uint4*)&Ks1[row * 72 + g8] = *(const uint4*)(kb + (size_t)(s0 + 64 + row) * 3072 + g8);
      *(uint4*)&Vt0[row * 72 + g8] = *(const uint4*)(vb + (size_t)row * 1024 + s0 + g8);
      *(uint4*)&Vt1[row * 72 + g8] = *(const uint4*)(vb + (size_t)row * 1024 + s0 + 64 + g8);
    }
    __syncthreads();
    ull dw[2][4];
#pragma unroll
    for (int c2 = 0; c2 < 2; ++c2)
#pragma unroll
      for (int r = 0; r < 4; ++r)
        dw[c2][r] = depb[(size_t)(rowbase + quad * 4 + r) * 16 + ck0 + c2];
    f32x4 s[8];
#pragma unroll
    for (int j = 0; j < 8; ++j) {
      const us* kbuf = (j < 4) ? Ks0 : Ks1;
      const int row = (j & 3) * 16 + l16;
      bf16x8 bk0 = *(const bf16x8*)(const void*)&kbuf[row * 72 + quad * 8];
      bf16x8 bk1 = *(const bf16x8*)(const void*)&kbuf[row * 72 + 32 + quad * 8];
      f32x4 z = {};
      z = __builtin_amdgcn_mfma_f32_16x16x32_bf16(aq0, bk0, z, 0, 0, 0);
      z = __builtin_amdgcn_mfma_f32_16x16x32_bf16(aq1, bk1, z, 0, 0, 0);
      s[j] = z;
    }
    __syncthreads();
#pragma unroll
    for (int r = 0; r < 4; ++r) {
      const int trow = t0 + wv * 16 + quad * 4 + r;
      float mx = NEGINF;
#pragma unroll
      for (int j = 0; j < 8; ++j) {
        const int c2 = j >> 2;
        const int kl = (j & 3) * 16 + l16;
        const int kg = s0 + c2 * 64 + kl;
        bool ok = (kg <= trow) && ((dw[c2][r] >> kl) & 1ull);
        float sv = ok ? s[j][r] * 0.125f : NEGINF;
        s[j][r] = sv;
        mx = fmaxf(mx, sv);
      }
#pragma unroll
      for (int o2 = 8; o2; o2 >>= 1) mx = fmaxf(mx, __shfl_xor(mx, o2));
      const float mn = fmaxf(m_st[r], mx);
      const bool dead = (mn == NEGINF);
      const float alpha = dead ? 1.f : __expf(m_st[r] - mn);
      float rs = 0.f;
#pragma unroll
      for (int j = 0; j < 8; ++j) {
        float p = dead ? 0.f : __expf(s[j][r] - mn);
        s[j][r] = p;
        rs += p;
      }
#pragma unroll
      for (int o2 = 8; o2; o2 >>= 1) rs += __shfl_xor(rs, o2);
      m_st[r] = mn;
      l_st[r] = l_st[r] * alpha + rs;
#pragma unroll
      for (int jd = 0; jd < 4; ++jd) o[jd][r] *= alpha;
#pragma unroll
      for (int j = 0; j < 8; ++j)
        Ps[(wv * 16 + quad * 4 + r) * 136 + j * 16 + l16] = f2b(s[j][r]);
    }
    bf16x8 ap[4];
#pragma unroll
    for (int kk = 0; kk < 4; ++kk)
      ap[kk] = *(const bf16x8*)(const void*)&Ps[(wv * 16 + l16) * 136 + kk * 32 + quad * 8];
#pragma unroll
    for (int jd = 0; jd < 4; ++jd) {
      bf16x8 b0 = *(const bf16x8*)(const void*)&Vt0[(jd * 16 + l16) * 72 + quad * 8];
      bf16x8 b1 = *(const bf16x8*)(const void*)&Vt0[(jd * 16 + l16) * 72 + 32 + quad * 8];
      bf16x8 b2 = *(const bf16x8*)(const void*)&Vt1[(jd * 16 + l16) * 72 + quad * 8];
      bf16x8 b3 = *(const bf16x8*)(const void*)&Vt1[(jd * 16 + l16) * 72 + 32 + quad * 8];
      o[jd] = __builtin_amdgcn_mfma_f32_16x16x32_bf16(ap[0], b0, o[jd], 0, 0, 0);
      o[jd] = __builtin_amdgcn_mfma_f32_16x16x32_bf16(ap[1], b1, o[jd], 0, 0, 0);
      o[jd] = __builtin_amdgcn_mfma_f32_16x16x32_bf16(ap[2], b2, o[jd], 0, 0, 0);
      o[jd] = __builtin_amdgcn_mfma_f32_16x16x32_bf16(ap[3], b3, o[jd], 0, 0, 0);
    }
  }
#pragma unroll
  for (int r = 0; r < 4; ++r) {
    const float inv = (l_st[r] > 0.f) ? 1.f / l_st[r] : 0.f;
#pragma unroll
    for (int jd = 0; jd < 4; ++jd)
      y[(size_t)(rowbase + quad * 4 + r) * 1024 + h * 64 + jd * 16 + l16] = f2b(o[jd][r] * inv);
  }
}

DEVI void hat_body(us* Kst0, us* Vtt0, const us* qkv,
                   const us* vsT, const us* vhT,
                   const ull* starb, const ull* hatb, const ull* depb,
                   const int* bflags, us* y, int b, int h, int tt, int t) {
  us* Kst1 = Kst0 + 64 * 72;
  us* Vtt1 = Vtt0 + 64 * 72;
  us* Ps = Kst0;
  const int wv = t >> 6, lane = t & 63;
  const int l16 = lane & 15, quad = lane >> 4;
  const int t0 = tt * 64;
  const int rowbase = b * 1024 + t0 + wv * 16;
  const us* qp = qkv + (size_t)(2048 + rowbase + l16) * 3072 + h * 64 + quad * 8;
  bf16x8 aq0 = *(const bf16x8*)(qp);
  bf16x8 aq1 = *(const bf16x8*)(qp + 32);
  const us* ksb = qkv + (size_t)(b * 1024) * 3072 + 1024 + h * 64;
  const us* khb = qkv + (size_t)(2048 + b * 1024) * 3072 + 1024 + h * 64;
  const us* vsb = vsT + (size_t)(b * 16 + h) * 65536;
  const us* vhb = vhT + (size_t)(b * 16 + h) * 65536;
  float m_st[4] = {NEGINF, NEGINF, NEGINF, NEGINF};
  float l_st[4] = {0.f, 0.f, 0.f, 0.f};
  f32x4 o[4] = {};
  for (int ck = 0; ck < 16; ++ck) {
    if (bflags[(b * 16 + tt) * 16 + ck] == 0) continue;
    const int s0 = ck * 64;
    __syncthreads();
#pragma unroll
    for (int it = 0; it < 2; ++it) {
      int id = it * 256 + t; int row = id >> 3, g8 = (id & 7) * 8;
      *(uint4*)&Kst0[row * 72 + g8] = *(const uint4*)(ksb + (size_t)(s0 + row) * 3072 + g8);
      *(uint4*)&Kst1[row * 72 + g8] = *(const uint4*)(khb + (size_t)(s0 + row) * 3072 + g8);
      *(uint4*)&Vtt0[row * 72 + g8] = *(const uint4*)(vsb + (size_t)row * 1024 + s0 + g8);
      *(uint4*)&Vtt1[row * 72 + g8] = *(const uint4*)(vhb + (size_t)row * 1024 + s0 + g8);
    }
    __syncthreads();
    ull as_[4], ah_[4];
#pragma unroll
    for (int r = 0; r < 4; ++r) {
      const size_t mrow = (size_t)(rowbase + quad * 4 + r) * 16 + ck;
      const ull dwm = depb[mrow];
      as_[r] = starb[mrow] & dwm;
      ah_[r] = hatb[mrow] & dwm;
    }
    f32x4 s[8];
#pragma unroll
    for (int j = 0; j < 8; ++j) {
      const us* kbuf = (j < 4) ? Kst0 : Kst1;
      const int row = (j & 3) * 16 + l16;
      bf16x8 bk0 = *(const bf16x8*)(const void*)&kbuf[row * 72 + quad * 8];
      bf16x8 bk1 = *(const bf16x8*)(const void*)&kbuf[row * 72 + 32 + quad * 8];
      f32x4 z = {};
      z = __builtin_amdgcn_mfma_f32_16x16x32_bf16(aq0, bk0, z, 0, 0, 0);
      z = __builtin_amdgcn_mfma_f32_16x16x32_bf16(aq1, bk1, z, 0, 0, 0);
      s[j] = z;
    }
    __syncthreads();
#pragma unroll
    for (int r = 0; r < 4; ++r) {
      float mx = NEGINF;
#pragma unroll
      for (int j = 0; j < 8; ++j) {
        const int kl = (j & 3) * 16 + l16;
        const ull act = (j < 4) ? as_[r] : ah_[r];
        bool ok = ((act >> kl) & 1ull) != 0;
        float sv = ok ? s[j][r] * 0.125f : NEGINF;
        s[j][r] = sv;
        mx = fmaxf(mx, sv);
      }
#pragma unroll
      for (int o2 = 8; o2; o2 >>= 1) mx = fmaxf(mx, __shfl_xor(mx, o2));
      const float mn = fmaxf(m_st[r], mx);
      const bool dead = (mn == NEGINF);
      const float alpha = dead ? 1.f : __expf(m_st[r] - mn);
      float rs = 0.f;
#pragma unroll
      for (int j = 0; j < 8; ++j) {
        float p = dead ? 0.f : __expf(s[j][r] - mn);
        s[j][r] = p;
        rs += p;
      }
#pragma unroll
      for (int o2 = 8; o2; o2 >>= 1) rs += __shfl_xor(rs, o2);
      m_st[r] = mn;
      l_st[r] = l_st[r] * alpha + rs;
#pragma unroll
      for (int jd = 0; jd < 4; ++jd) o[jd][r] *= alpha;
#pragma unroll
      for (int j = 0; j < 8; ++j)
        Ps[(wv * 16 + quad * 4 + r) * 136 + j * 16 + l16] = f2b(s[j][r]);
    }
    bf16x8 ap[4];
#pragma unroll
    for (int kk = 0; kk < 4; ++kk)
      ap[kk] = *(const bf16x8*)(const void*)&Ps[(wv * 16 + l16) * 136 + kk * 32 + quad * 8];
#pragma unroll
    for (int jd = 0; jd < 4; ++jd) {
      bf16x8 b0 = *(const bf16x8*)(const void*)&Vtt0[(jd * 16 + l16) * 72 + quad * 8];
      bf16x8 b1 = *(const bf16x8*)(const void*)&Vtt0[(jd * 16 + l16) * 72 + 32 + quad * 8];
      bf16x8 b2 = *(const bf16x8*)(const void*)&Vtt1[(jd * 16 + l16) * 72 + quad * 8];
      bf16x8 b3 = *(const bf16x8*)(const void*)&Vtt1[(jd * 16 + l16) * 72 + 32 + quad * 8];
      o[jd] = __builtin_amdgcn_mfma_f32_16x16x32_bf16(ap[0], b0, o[jd], 0, 0, 0);
      o[jd] = __builtin_amdgcn_mfma_f32_16x16x32_bf16(ap[1], b1, o[jd], 0, 0, 0);
      o[jd] = __builtin_amdgcn_mfma_f32_16x16x32_bf16(ap[2], b2, o[jd], 0, 0, 0);
      o[jd] = __builtin_amdgcn_mfma_f32_16x16x32_bf16(ap[3], b3, o[jd], 0, 0, 0);
    }
  }
#pragma unroll
  for (int r = 0; r < 4; ++r) {
    const float inv = (l_st[r] > 0.f) ? 1.f / l_st[r] : 0.f;
#pragma unroll
    for (int jd = 0; jd < 4; ++jd)
      y[(size_t)(2048 + rowbase + quad * 4 + r) * 1024 + h * 64 + jd * 16 + l16] = f2b(o[jd][r] * inv);
  }
}

// XCD-swizzled merged self-attention: group g=(gq*8+xcd) in 0..63 pins all 16
// tt-tiles of one (stream,b,h) to one XCD (K/V working set ~512KB -> L2-resident).
__global__ __launch_bounds__(256) void self_attn_mfma(
    const us* __restrict__ qkv,
    const us* __restrict__ vstT, const us* __restrict__ vhtT,
    const ull* __restrict__ sbits, const ull* __restrict__ hbits,
    const ull* __restrict__ dbits, const int* __restrict__ bflags,
    us* __restrict__ y) {
  __shared__ __attribute__((aligned(16))) us Kbuf[2][64 * 72];
  __shared__ __attribute__((aligned(16))) us Vbuf[2][64 * 72];
  const int bid = blockIdx.x;
  const int xcd = bid & 7, tmp = bid >> 3;
  const int tt = tmp & 15, gq = tmp >> 4;
  const int g = gq * 8 + xcd;
  const int t = threadIdx.x;
  if (g < 32) {
    star_body(&Kbuf[0][0], &Vbuf[0][0], qkv, vstT, dbits, y, g >> 4, g & 15, tt, t);
  } else {
    const int g2 = g - 32;
    hat_body(&Kbuf[0][0], &Vbuf[0][0], qkv, vstT, vhtT, sbits, hbits, dbits, bflags,
             y, g2 >> 4, g2 & 15, tt, t);
  }
}

// ---------------------------------------------------------------------------
extern "C" void kernel_launch(void* const* d_in, const int* in_sizes, int n_in,
                              void* d_out, int out_size, void* d_ws, size_t ws_size,
                              hipStream_t stream) {
  const void* xs = d_in[0];
  const void* xh = d_in[1];
  const void* cc = d_in[2];
  const void* mstar = d_in[3];
  const void* mhat = d_in[4];
  const void* mdep = d_in[5];
  const void* ng = d_in[6];
  const void* nb = d_in[7];
  const void* Wq = d_in[8];
  const void* bq = d_in[9];
  const void* Wkv = d_in[10];
  const void* bkv = d_in[11];
  const void* Wco = d_in[12];
  const void* bco = d_in[13];
  const void* Wada = d_in[14];
  const void* bada = d_in[15];
  const void* Wqkv = d_in[16];
  const void* bqkv = d_in[17];
  const void* Wo = d_in[18];
  const void* bo = d_in[19];
  const void* W1 = d_in[20];
  const void* b1 = d_in[21];
  const void* W2 = d_in[22];
  const void* b2 = d_in[23];
  (void)in_sizes; (void)n_in; (void)out_size; (void)ws_size;

  char* ws = (char*)d_ws;
  size_t off = 0;
  auto alloc = [&](size_t bytes) -> char* {
    char* p = ws + off;
    off += (bytes + 255) & ~(size_t)255;
    return p;
  };
  int* flags = (int*)alloc(256);
  int* bflags = (int*)alloc(512 * 4);
  us* smallb = (us*)alloc(21504 * 2);
  us* ngb = smallb, *nbb = smallb + 1024, *bqb = smallb + 2048,
      *bkvb = smallb + 3072, *bcob = smallb + 5120, *badab = smallb + 6144,
      *bqkvb = smallb + 12288, *bob = smallb + 15360, *b1b = smallb + 16384,
      *b2b = smallb + 20480;
  us* WqT = (us*)alloc(1048576ull * 2);
  us* WkvT = (us*)alloc(2097152ull * 2);
  us* WcoT = (us*)alloc(1048576ull * 2);
  us* WadaT = (us*)alloc(6291456ull * 2);
  us* WqkvT = (us*)alloc(3145728ull * 2);
  us* WoT = (us*)alloc(1048576ull * 2);
  us* W1T = (us*)alloc(4194304ull * 2);
  us* W2T = (us*)alloc(4194304ull * 2);
  us* xn = (us*)alloc(4194304ull * 2);
  us* qb = (us*)alloc(4194304ull * 2);
  us* kvb = (us*)alloc(1048576ull * 2);
  us* gada = (us*)alloc(25165824ull * 2);
  us* msb = (us*)alloc(4194304ull * 2);
  us* qkvb = (us*)alloc(12582912ull * 2);
  float* x1 = (float*)alloc(4194304ull * 4);
  us* hid = (us*)alloc(16777216ull * 2);
  ull* mb = (ull*)alloc(3ull * 32768 * 8);
  us* kvT = (us*)alloc(524288ull * 2);
  us* vstT = (us*)alloc(2097152ull * 2);
  us* vhtT = (us*)alloc(2097152ull * 2);

  ull* sbits = mb;
  ull* hbits = mb + 32768;
  ull* dbits = mb + 65536;
  us* ccb = hid;              // dead before hid written
  us* lnx = hid + 1048576;    // dead before hid written
  us* yca = xn;
  us* silub = qb;
  us* yat = msb;

  dim3 blk(256);
  detect_flags<<<1, blk, 0, stream>>>((const unsigned int*)xs, (const unsigned int*)mdep, flags);

  cvt_bf16<<<512, blk, 0, stream>>>(cc, ccb, 524288, flags);
  P10 ps10; ps10.p[0] = ng; ps10.p[1] = nb; ps10.p[2] = bq; ps10.p[3] = bkv;
  ps10.p[4] = bco; ps10.p[5] = bada; ps10.p[6] = bqkv; ps10.p[7] = bo;
  ps10.p[8] = b1; ps10.p[9] = b2;
  cvt_small<<<84, blk, 0, stream>>>(ps10, smallb, flags);

  transpose_cvt64<<<dim3(16, 16), blk, 0, stream>>>(Wq, WqT, 1024, 1024, flags);
  transpose_cvt64<<<dim3(16, 32), blk, 0, stream>>>(Wkv, WkvT, 1024, 2048, flags);
  transpose_cvt64<<<dim3(16, 16), blk, 0, stream>>>(Wco, WcoT, 1024, 1024, flags);
  transpose_cvt64<<<dim3(16, 96), blk, 0, stream>>>(Wada, WadaT, 1024, 6144, flags);
  transpose_cvt64<<<dim3(16, 48), blk, 0, stream>>>(Wqkv, WqkvT, 1024, 3072, flags);
  transpose_cvt64<<<dim3(16, 16), blk, 0, stream>>>(Wo, WoT, 1024, 1024, flags);
  transpose_cvt64<<<dim3(16, 64), blk, 0, stream>>>(W1, W1T, 1024, 4096, flags);
  transpose_cvt64<<<dim3(64, 16), blk, 0, stream>>>(W2, W2T, 4096, 1024, flags);

  P3 ps3; ps3.p[0] = mstar; ps3.p[1] = mhat; ps3.p[2] = mdep;
  pack_mask3<<<dim3(512, 3), blk, 0, stream>>>(ps3, mb, flags);
  hat_blockflags<<<32, blk, 0, stream>>>(sbits, hbits, bflags);

  ln_affine<<<4096, blk, 0, stream>>>(xs, xh, ngb, nbb, lnx, xn, flags);
  gemm_bt<EPI_BF16><<<dim3(32, 8), blk, 0, stream>>>(xn, WqT, bqb, qb, 4096, 1024, 1024, nullptr, nullptr, nullptr, nullptr);
  gemm_bt<EPI_BF16><<<dim3(4, 16), blk, 0, stream>>>(ccb, WkvT, bkvb, kvb, 512, 2048, 1024, nullptr, nullptr, nullptr, nullptr);
  vtrans<<<dim3(4, 32), blk, 0, stream>>>(kvb, kvT, 256, 2048, 1024, 0);
  cross_attn_mfma<<<1024, blk, 0, stream>>>(qb, kvb, kvT, yca);
  gemm_bt<EPI_SILU><<<dim3(32, 8), blk, 0, stream>>>(yca, WcoT, bcob, silub, 4096, 1024, 1024, nullptr, nullptr, nullptr, nullptr);
  gemm_bt<EPI_BF16><<<dim3(32, 48), blk, 0, stream>>>(silub, WadaT, badab, gada, 4096, 6144, 1024, nullptr, nullptr, nullptr, nullptr);
  mod_ms<<<4096, blk, 0, stream>>>(lnx, gada, msb);
  gemm_bt<EPI_BF16><<<dim3(32, 24), blk, 0, stream>>>(msb, WqkvT, bqkvb, qkvb, 4096, 3072, 1024, nullptr, nullptr, nullptr, nullptr);
  vtrans<<<dim3(16, 32), blk, 0, stream>>>(qkvb, vstT, 1024, 3072, 2048, 0);
  vtrans<<<dim3(16, 32), blk, 0, stream>>>(qkvb, vhtT, 1024, 3072, 2048, 2048);
  self_attn_mfma<<<1024, blk, 0, stream>>>(qkvb, vstT, vhtT, sbits, hbits, dbits, bflags, yat);
  gemm_bt<EPI_GATE_XRES><<<dim3(32, 8), blk, 0, stream>>>(yat, WoT, bob, x1, 4096, 1024, 1024, gada + 2048, xs, xh, flags);
  ln_mod<<<4096, blk, 0, stream>>>(x1, gada, msb);
  gemm_bt<EPI_GELU><<<dim3(32, 32), blk, 0, stream>>>(msb, W1T, b1b, hid, 4096, 4096, 1024, nullptr, nullptr, nullptr, nullptr);
  gemm_bt<EPI_GATE_OUT><<<dim3(32, 8), blk, 0, stream>>>(hid, W2T, b2b, d_out, 4096, 1024, 4096, gada + 5120, x1, nullptr, flags);
}